// Round 5
// baseline (2559.281 us; speedup 1.0000x reference)
//
#include <hip/hip_runtime.h>
#include <cstdint>
#include <cstddef>

#define BB 8
#define NN 8192
#define SS 2048
#define KNB 32

// Bit-exact squared distance matching numpy: (a-b) per component, squares,
// left-to-right sum, no FMA contraction.
__device__ __forceinline__ float sqdist_exact(float ax, float ay, float az,
                                              float bx, float by, float bz) {
#pragma clang fp contract(off)
    float dx = ax - bx;
    float dy = ay - by;
    float dz = az - bz;
    return (dx * dx + dy * dy) + dz * dz;
}

// u64 max (compare-select, ~3 VALU insts, branchless)
__device__ __forceinline__ unsigned long long u64max(unsigned long long a,
                                                     unsigned long long b) {
    return (a > b) ? a : b;
}

// DPP wave-64 reduce steps (gfx9 lineage: row_shr + row_bcast legal on CDNA4).
// u64 max step via DPP (2 dpp movs + u64 cmp/select, pure VALU). Identity 0
// is safe: keys are always non-negative (dist bits in the high half).
template <int CTRL>
__device__ __forceinline__ unsigned long long dpp_u64max_step(unsigned long long k) {
    int lo = __builtin_amdgcn_update_dpp(0, (int)(unsigned)(k & 0xffffffffu),
                                         CTRL, 0xf, 0xf, false);
    int hi = __builtin_amdgcn_update_dpp(0, (int)(unsigned)(k >> 32),
                                         CTRL, 0xf, 0xf, false);
    unsigned long long o = ((unsigned long long)(unsigned)hi << 32) | (unsigned)lo;
    return (o > k) ? o : k;
}
#define ROW_SHR1 0x111
#define ROW_SHR2 0x112
#define ROW_SHR4 0x114
#define ROW_SHR8 0x118
#define ROW_BC15 0x142
#define ROW_BC31 0x143

// ---------------------------------------------------------------------------
// Weight transpose prep: w1T[c][64], w2T[j][64], w3T[j][128]
// ---------------------------------------------------------------------------
__global__ void prep_kernel(const float* __restrict__ w1, const float* __restrict__ w2,
                            const float* __restrict__ w3, float* __restrict__ w1T,
                            float* __restrict__ w2T, float* __restrict__ w3T) {
    for (int i = threadIdx.x; i < 192; i += 256) {
        int oc = i / 3, c = i % 3;
        w1T[c * 64 + oc] = w1[i];
    }
    for (int i = threadIdx.x; i < 4096; i += 256) {
        int oc = i >> 6, j = i & 63;
        w2T[j * 64 + oc] = w2[i];
    }
    for (int i = threadIdx.x; i < 8192; i += 256) {
        int oc = i >> 6, j = i & 63;
        w3T[j * 128 + oc] = w3[i];
    }
}

// spread 3-bit value to bit positions 0,3,6
__device__ __forceinline__ int part3(int v) {
    return (v & 1) | ((v & 2) << 2) | ((v & 4) << 4);
}

#define PT_LIST(X) X(0) X(1) X(2) X(3) X(4) X(5) X(6) X(7) \
                   X(8) X(9) X(10) X(11) X(12) X(13) X(14) X(15)

// 16-way in-register min/max ILP trees over named regs a0..a15
#define MIN16(a)                                                             \
    fminf(fminf(fminf(fminf(a##0, a##1), fminf(a##2, a##3)),                 \
                fminf(fminf(a##4, a##5), fminf(a##6, a##7))),                \
          fminf(fminf(fminf(a##8, a##9), fminf(a##10, a##11)),               \
                fminf(fminf(a##12, a##13), fminf(a##14, a##15))))
#define MAX16(a)                                                             \
    fmaxf(fmaxf(fmaxf(fmaxf(a##0, a##1), fmaxf(a##2, a##3)),                 \
                fmaxf(fmaxf(a##4, a##5), fmaxf(a##6, a##7))),                \
          fmaxf(fmaxf(fmaxf(a##8, a##9), fmaxf(a##10, a##11)),               \
                fmaxf(fmaxf(a##12, a##13), fmaxf(a##14, a##15))))

// ---------------------------------------------------------------------------
// FPS — R16. Post-mortems: R14b (3460us) — 32 wave-uniform branches + serial
// per-brick DPP chains; R15 (2223us) — corner-distance bound too loose
// (~0.035 vs true ~0.006) -> ALL waves ran the busy path every iter, and at
// 2 waves/SIMD their VALU issue serialized (chip VALU 2.69% = 86% per active
// CU, issue-saturated). Lesson: the critical path is the slowest wave's busy
// path x SIMD issue contention; quiet waves are free only if waves actually
// go quiet, and the bound must be TIGHT.
// R16: per-THREAD granularity (R12 thread-contiguous layout, one ~0.125-wide
// Morton cell per thread):
//   - per-thread bbox: in-register min/max trees over own 16 regs (no
//     cross-lane ops, one-time).
//   - per-thread prune bound ubr = the thread's EXACT max min-dist (hi word
//     of its cached argmax key) — tightest bound at 16-pt granularity,
//     rebuilt only when the thread updates. act = lb2*0.999 < ubr. Skip is
//     exact: d^2 >= lb2 >= ubr >= dist_p for every own p.
//   - ballot(act)==0 -> wave writes cached waveKey, straight to barrier.
//     Else: lane-masked update+rekey (16 sqdist+fmin; 15-node u64max ILP
//     tree; cache klo/khi/ubr), then ONE full-exec 6-step DPP u64max over
//     the 64 cached per-lane keys (unchanged lanes' keys exact) -> lane 63
//     writes red. Ordering semantics identical (max dist, then min orig
//     index via ~od precomputed at init).
// Cross-wave tail, Morton sort, one barrier/iter parity double-buffer all
// unchanged (verified R0-R4 correctness runs).
// ---------------------------------------------------------------------------
__global__ __attribute__((amdgpu_flat_work_group_size(512, 512),
                          amdgpu_waves_per_eu(2, 2)))
void fps_kernel(const float* __restrict__ xyz_all,
                float4* __restrict__ wsSorted,
                float4* __restrict__ wsCtr,
                float* __restrict__ out0) {
    const int b = blockIdx.x;
    const float* xyz = xyz_all + (size_t)b * NN * 3;
    float4* sorted = wsSorted + (size_t)b * NN;
    float4* ctr = wsCtr + (size_t)b * SS;
    float* o0 = out0 + (size_t)b * 3 * SS;

    __shared__ float xLds[NN];            // 32KB
    __shared__ float yLds[NN];            // 32KB
    __shared__ float zLds[NN];            // 32KB
    __shared__ float4 ctrLds[SS];         // 32KB
    __shared__ int cellCnt[512];
    __shared__ int cellBase[512];
    __shared__ unsigned long long red[2][8];

    const int tid = threadIdx.x;
    const int wid = tid >> 6;
    const int lane = tid & 63;

    // --- pass 1: per-Morton-cell counts (16 pts/thread) + stage xyz in LDS
    cellCnt[tid] = 0;
    __syncthreads();
    int cellReg[16];
#pragma unroll
    for (int j = 0; j < 16; ++j) {
        int p = tid + j * 512;
        float x = xyz[p * 3 + 0], y = xyz[p * 3 + 1], z = xyz[p * 3 + 2];
        xLds[p] = x; yLds[p] = y; zLds[p] = z;
        int qx = min(7, (int)(x * 8.0f));
        int qy = min(7, (int)(y * 8.0f));
        int qz = min(7, (int)(z * 8.0f));
        cellReg[j] = part3(qx) | (part3(qy) << 1) | (part3(qz) << 2);
        atomicAdd(&cellCnt[cellReg[j]], 1);
    }
    __syncthreads();
    int myCnt = cellCnt[tid];
    // inclusive Hillis-Steele scan over 512 cells (thread==cell)
    for (int off = 1; off < 512; off <<= 1) {
        int v = (tid >= off) ? cellCnt[tid - off] : 0;
        __syncthreads();
        cellCnt[tid] += v;
        __syncthreads();
    }
    cellBase[tid] = cellCnt[tid] - myCnt;
    __syncthreads();
    // --- pass 2: scatter to global ws. Slot s stored at (s&15)*512 + (s>>4)
    // so read-back (thread t owns Morton slots 16t..16t+15) is coalesced.
#pragma unroll
    for (int j = 0; j < 16; ++j) {
        int p = tid + j * 512;
        float x = xLds[p], y = yLds[p], z = zLds[p];
        int pos = atomicAdd(&cellBase[cellReg[j]], 1);
        sorted[(pos & 15) * 512 + (pos >> 4)] = make_float4(x, y, z, __int_as_float(p));
    }
    __threadfence();
    __syncthreads();

    // --- load own 16 Morton-contiguous points (slots 16*tid..16*tid+15)
    // nd##i = ~original_index, precomputed for key packing.
#define DECL_PT(i)                          \
    float px##i, py##i, pz##i, dist##i;     \
    int nd##i;                              \
    {                                       \
        float4 v = sorted[i * 512 + tid];   \
        px##i = v.x; py##i = v.y; pz##i = v.z; \
        nd##i = ~__float_as_int(v.w);       \
        dist##i = 1e10f;                    \
    }
    PT_LIST(DECL_PT)

    // --- per-thread bbox over own 16 points (in-register trees, one-time)
    const float lox = MIN16(px), hix = MAX16(px);
    const float loy = MIN16(py), hiy = MAX16(py);
    const float loz = MIN16(pz), hiz = MAX16(pz);

    float cx = xLds[0], cy = yLds[0], cz = zLds[0];
    if (tid == 0) ctrLds[0] = make_float4(cx, cy, cz, 0.0f);

    // per-thread cached argmax key (klo,khi) and exact bound ubr (= key hi).
    // All lanes rebuild at s=1 (ubr=1e10 -> act), before first use.
    int klo = 0, khi = 0;
    float ubr = 1e10f;

    unsigned long long waveKey =
        ((unsigned long long)__float_as_uint(1e10f) << 32) | 0xFFFFFFFFull;

    for (int s = 1; s < SS; ++s) {
        const int par = s & 1;
        // per-thread exact prune: lower bound of center to own bbox vs own
        // exact max min-dist.
        float ddx = fmaxf(fmaxf(lox - cx, cx - hix), 0.0f);
        float ddy = fmaxf(fmaxf(loy - cy, cy - hiy), 0.0f);
        float ddz = fmaxf(fmaxf(loz - cz, cz - hiz), 0.0f);
        float lb2 = (ddx * ddx + ddy * ddy) + ddz * ddz;
        bool act = lb2 * 0.999f < ubr;
        if (__ballot(act)) {
            if (act) {
                // update own 16 dists
#define UPD_PT(i)                                                     \
    {                                                                 \
        float d = sqdist_exact(px##i, py##i, pz##i, cx, cy, cz);      \
        dist##i = fminf(dist##i, d);                                  \
    }
                PT_LIST(UPD_PT)
                // rebuild own key: 15-node u64max ILP tree over
                // (dist bits << 32) | ~od
#define KEY_PT(i)                                                     \
    unsigned long long k##i =                                         \
        ((unsigned long long)__float_as_uint(dist##i) << 32) |        \
        (unsigned)nd##i;
                PT_LIST(KEY_PT)
                unsigned long long t0 = u64max(k0, k1), t1 = u64max(k2, k3),
                                   t2 = u64max(k4, k5), t3 = u64max(k6, k7),
                                   t4 = u64max(k8, k9), t5 = u64max(k10, k11),
                                   t6 = u64max(k12, k13), t7 = u64max(k14, k15);
                unsigned long long u0 = u64max(t0, t1), u1 = u64max(t2, t3),
                                   u2 = u64max(t4, t5), u3 = u64max(t6, t7);
                unsigned long long Kt = u64max(u64max(u0, u1), u64max(u2, u3));
                klo = (int)(unsigned)(Kt & 0xffffffffu);
                khi = (int)(unsigned)(Kt >> 32);
                ubr = __int_as_float(khi);
            }
            // full-exec cross-lane reduce over the 64 cached keys
            unsigned long long K =
                ((unsigned long long)(unsigned)khi << 32) | (unsigned)klo;
            K = dpp_u64max_step<ROW_SHR1>(K);
            K = dpp_u64max_step<ROW_SHR2>(K);
            K = dpp_u64max_step<ROW_SHR4>(K);
            K = dpp_u64max_step<ROW_SHR8>(K);
            K = dpp_u64max_step<ROW_BC15>(K);
            K = dpp_u64max_step<ROW_BC31>(K);
            if (lane == 63) red[par][wid] = K;
            // refresh cached uniform wave key (for future quiet iterations)
            unsigned wlo = (unsigned)__builtin_amdgcn_readlane(
                (int)(unsigned)(K & 0xffffffffu), 63);
            unsigned whi = (unsigned)__builtin_amdgcn_readlane(
                (int)(unsigned)(K >> 32), 63);
            waveKey = ((unsigned long long)whi << 32) | wlo;
        } else {
            if (lane == 0) red[par][wid] = waveKey;
        }
        __syncthreads();  // lgkm-only drain (no global ops in loop)
        // cross-wave reduce: ONE lane-indexed b64 read + 3 DPP row_shr u64-max
        // steps (lane 7 of each 16-row = max over slots 0..7); the winning
        // index is the low half of the max key -> one readlane, no ballot.
        unsigned long long k = red[par][lane & 7];
        k = dpp_u64max_step<ROW_SHR1>(k);
        k = dpp_u64max_step<ROW_SHR2>(k);
        k = dpp_u64max_step<ROW_SHR4>(k);
        unsigned blo = (unsigned)__builtin_amdgcn_readlane(
            (int)(unsigned)(k & 0xffffffffu), 7);
        int wiu = (int)(~blo);  // uniform (SGPR) winner index
        cx = xLds[wiu];  // 3 independent broadcast ds_read_b32
        cy = yLds[wiu];
        cz = zLds[wiu];
        if (tid == 0) ctrLds[s] = make_float4(cx, cy, cz, 0.0f);
    }

    // --- single coalesced write-out of all centers
    __syncthreads();
    for (int s = tid; s < SS; s += 512) {
        float4 c = ctrLds[s];
        o0[s] = c.x;
        o0[SS + s] = c.y;
        o0[2 * SS + s] = c.z;
        ctr[s] = c;
    }
}

// ---------------------------------------------------------------------------
// Fused ball-query + MLP + maxpool. Block = 128 threads (2 waves), 2 centers.
// LDS halved (R9): h2 reuses h1's buffer in place -> ~17KB -> ~9 blocks/CU.
// ---------------------------------------------------------------------------
__global__ __launch_bounds__(128) void bqmlp_kernel(const float* __restrict__ xyz_all,
                                                    const float4* __restrict__ wsCtr,
                                                    const float* __restrict__ w1T,
                                                    const float* __restrict__ b1,
                                                    const float* __restrict__ w2T,
                                                    const float* __restrict__ b2,
                                                    const float* __restrict__ w3T,
                                                    const float* __restrict__ b3,
                                                    float* __restrict__ out1) {
    const int b = blockIdx.x >> 10;            // 1024 blocks per batch
    const int s0 = (blockIdx.x & 1023) * 2;    // 2 centers per block
    const float* xyz = xyz_all + (size_t)b * NN * 3;

    __shared__ float relF[2 * KNB * 3];  // [64 rows][3]
    __shared__ float hT[64 * 64];        // [ch][row] — holds h1, then h2

    const int tid = threadIdx.x;
    const int cb = __builtin_amdgcn_readfirstlane(tid >> 6);  // wave id (uniform)
    const int l = tid & 63;

    // ---- ball query: wave cb handles center s0+cb
    {
        float4 cc = wsCtr[(size_t)b * SS + s0 + cb];
        float ccx = cc.x, ccy = cc.y, ccz = cc.z;
        const float R2 = (float)(0.2 * 0.2);
        int total = 0;
        float fx = 0.f, fy = 0.f, fz = 0.f;
        bool have = false;
        for (int chunk = 0; chunk < 128 && total < KNB; ++chunk) {
            int p = chunk * 64 + l;
            float x = xyz[p * 3 + 0], y = xyz[p * 3 + 1], z = xyz[p * 3 + 2];
            float d = sqdist_exact(ccx, ccy, ccz, x, y, z);
            bool hit = (d <= R2);
            unsigned long long mask = __ballot(hit);
            int cnt = __popcll(mask);
            if (cnt) {
                int pos = total + __popcll(mask & ((1ull << l) - 1ull));
                float rx = x - ccx, ry = y - ccy, rz = z - ccz;  // single subs: exact
                if (hit && pos < KNB) {
                    relF[(cb * KNB + pos) * 3 + 0] = rx;
                    relF[(cb * KNB + pos) * 3 + 1] = ry;
                    relF[(cb * KNB + pos) * 3 + 2] = rz;
                }
                if (hit && pos == 0) { fx = rx; fy = ry; fz = rz; have = true; }
                total += cnt;
            }
        }
        unsigned long long hm = __ballot(have);
        if (total < KNB) {
            int src = __ffsll((long long)hm) - 1;
            float gx = __shfl(fx, src), gy = __shfl(fy, src), gz = __shfl(fz, src);
            if (l >= total && l < KNB) {
                relF[(cb * KNB + l) * 3 + 0] = gx;
                relF[(cb * KNB + l) * 3 + 1] = gy;
                relF[(cb * KNB + l) * 3 + 2] = gz;
            }
        }
    }
    __syncthreads();

    const int r = l;  // row 0..63: rows 0..31 center s0, rows 32..63 center s0+1

    // ---- layer 1: rel(3) -> 64, thread covers ch block cb*32..+31 for row r
    {
        float rx = relF[r * 3 + 0], ry = relF[r * 3 + 1], rz = relF[r * 3 + 2];
#pragma unroll
        for (int i = 0; i < 32; ++i) {
            int ch = cb * 32 + i;
            float h = b1[ch];
            h = fmaf(rx, w1T[0 * 64 + ch], h);
            h = fmaf(ry, w1T[1 * 64 + ch], h);
            h = fmaf(rz, w1T[2 * 64 + ch], h);
            hT[ch * 64 + r] = fmaxf(h, 0.0f);
        }
    }
    __syncthreads();

    // ---- layer 2: 64 -> 64 (reads h1 from hT; after barrier, h2 overwrites)
    {
        float acc[32];
#pragma unroll
        for (int i = 0; i < 32; ++i) acc[i] = b2[cb * 32 + i];
#pragma unroll 4
        for (int j = 0; j < 64; ++j) {
            float a = hT[j * 64 + r];
            const float* wrow = w2T + j * 64 + cb * 32;
#pragma unroll
            for (int i = 0; i < 32; ++i) acc[i] = fmaf(a, wrow[i], acc[i]);
        }
        __syncthreads();  // all h1 reads complete before overwrite
#pragma unroll
        for (int i = 0; i < 32; ++i) hT[(cb * 32 + i) * 64 + r] = fmaxf(acc[i], 0.0f);
    }
    __syncthreads();

    // ---- layer 3: 64 -> 128, fused relu + maxpool over the 32 rows/center
    {
        float acc[64];
#pragma unroll
        for (int i = 0; i < 64; ++i) acc[i] = b3[cb * 64 + i];
#pragma unroll 2
        for (int j = 0; j < 64; ++j) {
            float a = hT[j * 64 + r];
            const float* wrow = w3T + j * 128 + cb * 64;
#pragma unroll
            for (int i = 0; i < 64; ++i) acc[i] = fmaf(a, wrow[i], acc[i]);
        }
#pragma unroll
        for (int i = 0; i < 64; ++i) {
            float v = fmaxf(acc[i], 0.0f);
            v = fmaxf(v, __shfl_xor(v, 1));
            v = fmaxf(v, __shfl_xor(v, 2));
            v = fmaxf(v, __shfl_xor(v, 4));
            v = fmaxf(v, __shfl_xor(v, 8));
            v = fmaxf(v, __shfl_xor(v, 16));
            acc[i] = v;
        }
        if ((l & 31) == 0) {
            int sA = s0 + (l >> 5);
            float* op = out1 + ((size_t)b * 128 + cb * 64) * SS + sA;
#pragma unroll
            for (int i = 0; i < 64; ++i) op[(size_t)i * SS] = acc[i];
        }
    }
}

extern "C" void kernel_launch(void* const* d_in, const int* in_sizes, int n_in,
                              void* d_out, int out_size, void* d_ws, size_t ws_size,
                              hipStream_t stream) {
    (void)in_sizes; (void)n_in; (void)out_size; (void)ws_size;
    const float* xyz = (const float*)d_in[0];
    // d_in[1] = features : unused by the reference
    const float* w1 = (const float*)d_in[2];
    const float* b1 = (const float*)d_in[3];
    const float* w2 = (const float*)d_in[4];
    const float* b2 = (const float*)d_in[5];
    const float* w3 = (const float*)d_in[6];
    const float* b3 = (const float*)d_in[7];
    float* out = (float*)d_out;

    // workspace layout
    float4* wsCtr = (float4*)d_ws;              // B*S float4      (256 KB)
    float4* wsSorted = wsCtr + BB * SS;         // B*N float4      (1 MB)
    float* w1T = (float*)(wsSorted + BB * NN);  // 192 f
    float* w2T = w1T + 192;                     // 4096 f
    float* w3T = w2T + 4096;                    // 8192 f

    prep_kernel<<<1, 256, 0, stream>>>(w1, w2, w3, w1T, w2T, w3T);
    fps_kernel<<<BB, 512, 0, stream>>>(xyz, wsSorted, wsCtr, out);
    bqmlp_kernel<<<BB * (SS / 2), 128, 0, stream>>>(xyz, wsCtr, w1T, b1, w2T, b2,
                                                    w3T, b3, out + BB * 3 * SS);
}

// Round 6
// 2026.327 us; speedup vs baseline: 1.2630x; 1.2630x over previous
//
#include <hip/hip_runtime.h>
#include <cstdint>
#include <cstddef>

#define BB 8
#define NN 8192
#define SS 2048
#define KNB 32

// Bit-exact squared distance matching numpy: (a-b) per component, squares,
// left-to-right sum, no FMA contraction.
__device__ __forceinline__ float sqdist_exact(float ax, float ay, float az,
                                              float bx, float by, float bz) {
#pragma clang fp contract(off)
    float dx = ax - bx;
    float dy = ay - by;
    float dz = az - bz;
    return (dx * dx + dy * dy) + dz * dz;
}

// u64 max (compare-select, ~3 VALU insts, branchless)
__device__ __forceinline__ unsigned long long u64max(unsigned long long a,
                                                     unsigned long long b) {
    return (a > b) ? a : b;
}

// DPP wave-64 reduce steps (gfx9 lineage: row_shr + row_bcast legal on CDNA4).
// u64 max step via DPP (2 dpp movs + u64 cmp/select, pure VALU). Identity 0
// is safe: keys are always non-negative (dist bits in the high half).
template <int CTRL>
__device__ __forceinline__ unsigned long long dpp_u64max_step(unsigned long long k) {
    int lo = __builtin_amdgcn_update_dpp(0, (int)(unsigned)(k & 0xffffffffu),
                                         CTRL, 0xf, 0xf, false);
    int hi = __builtin_amdgcn_update_dpp(0, (int)(unsigned)(k >> 32),
                                         CTRL, 0xf, 0xf, false);
    unsigned long long o = ((unsigned long long)(unsigned)hi << 32) | (unsigned)lo;
    return (o > k) ? o : k;
}
#define ROW_SHR1 0x111
#define ROW_SHR2 0x112
#define ROW_SHR4 0x114
#define ROW_SHR8 0x118
#define ROW_BC15 0x142
#define ROW_BC31 0x143

// full-wave min/max butterfly (init-time only, not on the hot path)
__device__ __forceinline__ void wave_minmax(float x, float& lo, float& hi) {
    float a = x, b = x;
#pragma unroll
    for (int off = 1; off < 64; off <<= 1) {
        a = fminf(a, __shfl_xor(a, off));
        b = fmaxf(b, __shfl_xor(b, off));
    }
    lo = a;
    hi = b;
}

// ---------------------------------------------------------------------------
// Weight transpose prep: w1T[c][64], w2T[j][64], w3T[j][128]
// ---------------------------------------------------------------------------
__global__ void prep_kernel(const float* __restrict__ w1, const float* __restrict__ w2,
                            const float* __restrict__ w3, float* __restrict__ w1T,
                            float* __restrict__ w2T, float* __restrict__ w3T) {
    for (int i = threadIdx.x; i < 192; i += 256) {
        int oc = i / 3, c = i % 3;
        w1T[c * 64 + oc] = w1[i];
    }
    for (int i = threadIdx.x; i < 4096; i += 256) {
        int oc = i >> 6, j = i & 63;
        w2T[j * 64 + oc] = w2[i];
    }
    for (int i = threadIdx.x; i < 8192; i += 256) {
        int oc = i >> 6, j = i & 63;
        w3T[j * 128 + oc] = w3[i];
    }
}

// spread 3-bit value to bit positions 0,3,6
__device__ __forceinline__ int part3(int v) {
    return (v & 1) | ((v & 2) << 2) | ((v & 4) << 4);
}

#define PT_LIST(X) X(0) X(1) X(2) X(3) X(4) X(5) X(6) X(7) \
                   X(8) X(9) X(10) X(11) X(12) X(13) X(14) X(15)

// ---------------------------------------------------------------------------
// FPS — R17. Measured ladder: R12 1690 / R13 1670 / R15 2223 / R16 2265.
// Lesson distilled: with 2 waves/SIMD, symmetric always-busy waves hide each
// other's dependent-chain latency; pruning that idles the partner wave
// EXPOSES the active wave's latency (an active wave always exists — the new
// center's own cell must update), so asymmetric schedules lose. Issue count
// alone is not the critical path (R13 cut VALU 30%, time flat).
// R17 = R13's verified-best symmetric structure with ONE change: the busy
// path's two-phase reduce (serial 16-deep fmax chain + 6 DPP fmax + readlane
// + serial 16-deep select chain + 6 DPP imin + readlane, ~130 insts, ~300cy
// serial) is replaced by the joint u64 argmax proven in R15/R16: pack
// (dist<<32 | ~od) (~od precomputed at init), 15-node ILP tree (depth 4),
// ONE 6-step DPP u64max chain, lane63 writes red directly; 2 readlanes
// refresh the cached waveKey + wave_bv. ~110 insts, ~170cy serial. Ordering
// semantics identical (max dist, tie -> min orig index). Everything else
// byte-identical to R13: brick layout (reg i = 64 consecutive Morton slots),
// per-brick wave-uniform masked updates vs wave_bv, brick bboxes in lanes
// 0..15, Morton sort, cross-wave tail, one barrier/iter parity buffer.
// ---------------------------------------------------------------------------
__global__ __attribute__((amdgpu_flat_work_group_size(512, 512),
                          amdgpu_waves_per_eu(2, 2)))
void fps_kernel(const float* __restrict__ xyz_all,
                float4* __restrict__ wsSorted,
                float4* __restrict__ wsCtr,
                float* __restrict__ out0) {
    const int b = blockIdx.x;
    const float* xyz = xyz_all + (size_t)b * NN * 3;
    float4* sorted = wsSorted + (size_t)b * NN;
    float4* ctr = wsCtr + (size_t)b * SS;
    float* o0 = out0 + (size_t)b * 3 * SS;

    __shared__ float xLds[NN];            // 32KB
    __shared__ float yLds[NN];            // 32KB
    __shared__ float zLds[NN];            // 32KB
    __shared__ float4 ctrLds[SS];         // 32KB
    __shared__ int cellCnt[512];
    __shared__ int cellBase[512];
    __shared__ unsigned long long red[2][8];

    const int tid = threadIdx.x;
    const int wid = tid >> 6;
    const int lane = tid & 63;

    // --- pass 1: per-Morton-cell counts (16 pts/thread) + stage xyz in LDS
    cellCnt[tid] = 0;
    __syncthreads();
    int cellReg[16];
#pragma unroll
    for (int j = 0; j < 16; ++j) {
        int p = tid + j * 512;
        float x = xyz[p * 3 + 0], y = xyz[p * 3 + 1], z = xyz[p * 3 + 2];
        xLds[p] = x; yLds[p] = y; zLds[p] = z;
        int qx = min(7, (int)(x * 8.0f));
        int qy = min(7, (int)(y * 8.0f));
        int qz = min(7, (int)(z * 8.0f));
        cellReg[j] = part3(qx) | (part3(qy) << 1) | (part3(qz) << 2);
        atomicAdd(&cellCnt[cellReg[j]], 1);
    }
    __syncthreads();
    int myCnt = cellCnt[tid];
    // inclusive Hillis-Steele scan over 512 cells (thread==cell)
    for (int off = 1; off < 512; off <<= 1) {
        int v = (tid >= off) ? cellCnt[tid - off] : 0;
        __syncthreads();
        cellCnt[tid] += v;
        __syncthreads();
    }
    cellBase[tid] = cellCnt[tid] - myCnt;
    __syncthreads();
    // --- pass 2: scatter to global ws in PLAIN Morton-slot order. The reader
    // (reg j, lane l <-> slot (wid*16+j)*64 + l) is coalesced directly.
#pragma unroll
    for (int j = 0; j < 16; ++j) {
        int p = tid + j * 512;
        float x = xLds[p], y = yLds[p], z = zLds[p];
        int pos = atomicAdd(&cellBase[cellReg[j]], 1);
        sorted[pos] = make_float4(x, y, z, __int_as_float(p));
    }
    __threadfence();
    __syncthreads();

    // --- load own 16 regs: reg i = Morton slots [(wid*16+i)*64, +64), lane l
    // holds slot (wid*16+i)*64 + l. Wave covers [wid*1024, +1024).
    // nd##i = ~original_index, precomputed for key packing.
#define DECL_PT(i)                                      \
    float px##i, py##i, pz##i, dist##i;                 \
    int nd##i;                                          \
    {                                                   \
        float4 v = sorted[(wid * 16 + i) * 64 + lane];  \
        px##i = v.x; py##i = v.y; pz##i = v.z;          \
        nd##i = ~__float_as_int(v.w);                   \
        dist##i = 1e10f;                                \
    }
    PT_LIST(DECL_PT)

    // --- brick bboxes: brick i = reg i's 64 consecutive Morton slots.
    // Computed via shfl butterflies (one-time); lane i keeps brick i's bbox.
    float bbxlo = 0.f, bbxhi = 0.f, bbylo = 0.f, bbyhi = 0.f,
          bbzlo = 0.f, bbzhi = 0.f;
#define BRICK_BB(i)                                               \
    {                                                             \
        float xl, xh, yl, yh, zl, zh;                             \
        wave_minmax(px##i, xl, xh);                               \
        wave_minmax(py##i, yl, yh);                               \
        wave_minmax(pz##i, zl, zh);                               \
        if (lane == i) {                                          \
            bbxlo = xl; bbxhi = xh;                               \
            bbylo = yl; bbyhi = yh;                               \
            bbzlo = zl; bbzhi = zh;                               \
        }                                                         \
    }
    PT_LIST(BRICK_BB)

    float cx = xLds[0], cy = yLds[0], cz = zLds[0];
    if (tid == 0) ctrLds[0] = make_float4(cx, cy, cz, 0.0f);

    unsigned long long waveKey =
        ((unsigned long long)__float_as_uint(1e10f) << 32) | 0xFFFFFFFFull;
    float wave_bv = 1e10f;  // max min-dist over this wave's 1024 points (cached)

    for (int s = 1; s < SS; ++s) {
        const int par = s & 1;
        // brick-granular prune vs wave_bv (R13 semantics): lane i<16 tests
        // brick i's lower bound; skip is exact (lb2 >= wave_bv >= any dist).
        float ddx = fmaxf(fmaxf(bbxlo - cx, cx - bbxhi), 0.0f);
        float ddy = fmaxf(fmaxf(bbylo - cy, cy - bbyhi), 0.0f);
        float ddz = fmaxf(fmaxf(bbzlo - cz, cz - bbzhi), 0.0f);
        float lb2 = (ddx * ddx + ddy * ddy) + ddz * ddz;
        bool act = (lane < 16) && (lb2 * 0.999f < wave_bv);
        unsigned mask = (unsigned)__builtin_amdgcn_readfirstlane(
            (int)(unsigned)__ballot(act));
        if (mask) {
            // update dists of active bricks (wave-uniform scalar guards)
#define UPD_BR(i)                                                     \
    if (mask & (1u << i)) {                                           \
        float d = sqdist_exact(px##i, py##i, pz##i, cx, cy, cz);      \
        dist##i = fminf(dist##i, d);                                  \
    }
            PT_LIST(UPD_BR)
            // joint u64 argmax over all 16 regs (unchanged bricks keep
            // exact dists): key = (dist bits << 32) | ~od
#define KEY_PT(i)                                                     \
    unsigned long long k##i =                                         \
        ((unsigned long long)__float_as_uint(dist##i) << 32) |        \
        (unsigned)nd##i;
            PT_LIST(KEY_PT)
            // 4-level ILP tree over the 16 per-lane keys
            unsigned long long t0 = u64max(k0, k1), t1 = u64max(k2, k3),
                               t2 = u64max(k4, k5), t3 = u64max(k6, k7),
                               t4 = u64max(k8, k9), t5 = u64max(k10, k11),
                               t6 = u64max(k12, k13), t7 = u64max(k14, k15);
            unsigned long long u0 = u64max(t0, t1), u1 = u64max(t2, t3),
                               u2 = u64max(t4, t5), u3 = u64max(t6, t7);
            unsigned long long K = u64max(u64max(u0, u1), u64max(u2, u3));
            // cross-lane: ONE 6-step DPP u64max chain -> lane 63 writes red
            K = dpp_u64max_step<ROW_SHR1>(K);
            K = dpp_u64max_step<ROW_SHR2>(K);
            K = dpp_u64max_step<ROW_SHR4>(K);
            K = dpp_u64max_step<ROW_SHR8>(K);
            K = dpp_u64max_step<ROW_BC15>(K);
            K = dpp_u64max_step<ROW_BC31>(K);
            if (lane == 63) red[par][wid] = K;
            // refresh cached wave key + wave_bv (for future quiet iters)
            unsigned wlo = (unsigned)__builtin_amdgcn_readlane(
                (int)(unsigned)(K & 0xffffffffu), 63);
            unsigned whi = (unsigned)__builtin_amdgcn_readlane(
                (int)(unsigned)(K >> 32), 63);
            waveKey = ((unsigned long long)whi << 32) | wlo;
            wave_bv = __int_as_float((int)whi);
        } else {
            if (lane == 0) red[par][wid] = waveKey;
        }
        __syncthreads();  // lgkm-only drain (no global ops in loop)
        // cross-wave reduce: ONE lane-indexed b64 read + 3 DPP row_shr u64-max
        // steps (lane 7 of each 16-row = max over slots 0..7); the winning
        // index is the low half of the max key -> one readlane, no ballot.
        unsigned long long k = red[par][lane & 7];
        k = dpp_u64max_step<ROW_SHR1>(k);
        k = dpp_u64max_step<ROW_SHR2>(k);
        k = dpp_u64max_step<ROW_SHR4>(k);
        unsigned blo = (unsigned)__builtin_amdgcn_readlane(
            (int)(unsigned)(k & 0xffffffffu), 7);
        int wiu = (int)(~blo);  // uniform (SGPR) winner index
        cx = xLds[wiu];  // 3 independent broadcast ds_read_b32
        cy = yLds[wiu];
        cz = zLds[wiu];
        if (tid == 0) ctrLds[s] = make_float4(cx, cy, cz, 0.0f);
    }

    // --- single coalesced write-out of all centers
    __syncthreads();
    for (int s = tid; s < SS; s += 512) {
        float4 c = ctrLds[s];
        o0[s] = c.x;
        o0[SS + s] = c.y;
        o0[2 * SS + s] = c.z;
        ctr[s] = c;
    }
}

// ---------------------------------------------------------------------------
// Fused ball-query + MLP + maxpool. Block = 128 threads (2 waves), 2 centers.
// LDS halved (R9): h2 reuses h1's buffer in place -> ~17KB -> ~9 blocks/CU.
// ---------------------------------------------------------------------------
__global__ __launch_bounds__(128) void bqmlp_kernel(const float* __restrict__ xyz_all,
                                                    const float4* __restrict__ wsCtr,
                                                    const float* __restrict__ w1T,
                                                    const float* __restrict__ b1,
                                                    const float* __restrict__ w2T,
                                                    const float* __restrict__ b2,
                                                    const float* __restrict__ w3T,
                                                    const float* __restrict__ b3,
                                                    float* __restrict__ out1) {
    const int b = blockIdx.x >> 10;            // 1024 blocks per batch
    const int s0 = (blockIdx.x & 1023) * 2;    // 2 centers per block
    const float* xyz = xyz_all + (size_t)b * NN * 3;

    __shared__ float relF[2 * KNB * 3];  // [64 rows][3]
    __shared__ float hT[64 * 64];        // [ch][row] — holds h1, then h2

    const int tid = threadIdx.x;
    const int cb = __builtin_amdgcn_readfirstlane(tid >> 6);  // wave id (uniform)
    const int l = tid & 63;

    // ---- ball query: wave cb handles center s0+cb
    {
        float4 cc = wsCtr[(size_t)b * SS + s0 + cb];
        float ccx = cc.x, ccy = cc.y, ccz = cc.z;
        const float R2 = (float)(0.2 * 0.2);
        int total = 0;
        float fx = 0.f, fy = 0.f, fz = 0.f;
        bool have = false;
        for (int chunk = 0; chunk < 128 && total < KNB; ++chunk) {
            int p = chunk * 64 + l;
            float x = xyz[p * 3 + 0], y = xyz[p * 3 + 1], z = xyz[p * 3 + 2];
            float d = sqdist_exact(ccx, ccy, ccz, x, y, z);
            bool hit = (d <= R2);
            unsigned long long mask = __ballot(hit);
            int cnt = __popcll(mask);
            if (cnt) {
                int pos = total + __popcll(mask & ((1ull << l) - 1ull));
                float rx = x - ccx, ry = y - ccy, rz = z - ccz;  // single subs: exact
                if (hit && pos < KNB) {
                    relF[(cb * KNB + pos) * 3 + 0] = rx;
                    relF[(cb * KNB + pos) * 3 + 1] = ry;
                    relF[(cb * KNB + pos) * 3 + 2] = rz;
                }
                if (hit && pos == 0) { fx = rx; fy = ry; fz = rz; have = true; }
                total += cnt;
            }
        }
        unsigned long long hm = __ballot(have);
        if (total < KNB) {
            int src = __ffsll((long long)hm) - 1;
            float gx = __shfl(fx, src), gy = __shfl(fy, src), gz = __shfl(fz, src);
            if (l >= total && l < KNB) {
                relF[(cb * KNB + l) * 3 + 0] = gx;
                relF[(cb * KNB + l) * 3 + 1] = gy;
                relF[(cb * KNB + l) * 3 + 2] = gz;
            }
        }
    }
    __syncthreads();

    const int r = l;  // row 0..63: rows 0..31 center s0, rows 32..63 center s0+1

    // ---- layer 1: rel(3) -> 64, thread covers ch block cb*32..+31 for row r
    {
        float rx = relF[r * 3 + 0], ry = relF[r * 3 + 1], rz = relF[r * 3 + 2];
#pragma unroll
        for (int i = 0; i < 32; ++i) {
            int ch = cb * 32 + i;
            float h = b1[ch];
            h = fmaf(rx, w1T[0 * 64 + ch], h);
            h = fmaf(ry, w1T[1 * 64 + ch], h);
            h = fmaf(rz, w1T[2 * 64 + ch], h);
            hT[ch * 64 + r] = fmaxf(h, 0.0f);
        }
    }
    __syncthreads();

    // ---- layer 2: 64 -> 64 (reads h1 from hT; after barrier, h2 overwrites)
    {
        float acc[32];
#pragma unroll
        for (int i = 0; i < 32; ++i) acc[i] = b2[cb * 32 + i];
#pragma unroll 4
        for (int j = 0; j < 64; ++j) {
            float a = hT[j * 64 + r];
            const float* wrow = w2T + j * 64 + cb * 32;
#pragma unroll
            for (int i = 0; i < 32; ++i) acc[i] = fmaf(a, wrow[i], acc[i]);
        }
        __syncthreads();  // all h1 reads complete before overwrite
#pragma unroll
        for (int i = 0; i < 32; ++i) hT[(cb * 32 + i) * 64 + r] = fmaxf(acc[i], 0.0f);
    }
    __syncthreads();

    // ---- layer 3: 64 -> 128, fused relu + maxpool over the 32 rows/center
    {
        float acc[64];
#pragma unroll
        for (int i = 0; i < 64; ++i) acc[i] = b3[cb * 64 + i];
#pragma unroll 2
        for (int j = 0; j < 64; ++j) {
            float a = hT[j * 64 + r];
            const float* wrow = w3T + j * 128 + cb * 64;
#pragma unroll
            for (int i = 0; i < 64; ++i) acc[i] = fmaf(a, wrow[i], acc[i]);
        }
#pragma unroll
        for (int i = 0; i < 64; ++i) {
            float v = fmaxf(acc[i], 0.0f);
            v = fmaxf(v, __shfl_xor(v, 1));
            v = fmaxf(v, __shfl_xor(v, 2));
            v = fmaxf(v, __shfl_xor(v, 4));
            v = fmaxf(v, __shfl_xor(v, 8));
            v = fmaxf(v, __shfl_xor(v, 16));
            acc[i] = v;
        }
        if ((l & 31) == 0) {
            int sA = s0 + (l >> 5);
            float* op = out1 + ((size_t)b * 128 + cb * 64) * SS + sA;
#pragma unroll
            for (int i = 0; i < 64; ++i) op[(size_t)i * SS] = acc[i];
        }
    }
}

extern "C" void kernel_launch(void* const* d_in, const int* in_sizes, int n_in,
                              void* d_out, int out_size, void* d_ws, size_t ws_size,
                              hipStream_t stream) {
    (void)in_sizes; (void)n_in; (void)out_size; (void)ws_size;
    const float* xyz = (const float*)d_in[0];
    // d_in[1] = features : unused by the reference
    const float* w1 = (const float*)d_in[2];
    const float* b1 = (const float*)d_in[3];
    const float* w2 = (const float*)d_in[4];
    const float* b2 = (const float*)d_in[5];
    const float* w3 = (const float*)d_in[6];
    const float* b3 = (const float*)d_in[7];
    float* out = (float*)d_out;

    // workspace layout
    float4* wsCtr = (float4*)d_ws;              // B*S float4      (256 KB)
    float4* wsSorted = wsCtr + BB * SS;         // B*N float4      (1 MB)
    float* w1T = (float*)(wsSorted + BB * NN);  // 192 f
    float* w2T = w1T + 192;                     // 4096 f
    float* w3T = w2T + 4096;                    // 8192 f

    prep_kernel<<<1, 256, 0, stream>>>(w1, w2, w3, w1T, w2T, w3T);
    fps_kernel<<<BB, 512, 0, stream>>>(xyz, wsSorted, wsCtr, out);
    bqmlp_kernel<<<BB * (SS / 2), 128, 0, stream>>>(xyz, wsCtr, w1T, b1, w2T, b2,
                                                    w3T, b3, out + BB * 3 * SS);
}

// Round 7
// 1948.471 us; speedup vs baseline: 1.3135x; 1.0400x over previous
//
#include <hip/hip_runtime.h>
#include <cstdint>
#include <cstddef>

#define BB 8
#define NN 8192
#define SS 2048
#define KNB 32

typedef float f32x2 __attribute__((ext_vector_type(2)));

// Bit-exact squared distance matching numpy: (a-b) per component, squares,
// left-to-right sum, no FMA contraction.
__device__ __forceinline__ float sqdist_exact(float ax, float ay, float az,
                                              float bx, float by, float bz) {
#pragma clang fp contract(off)
    float dx = ax - bx;
    float dy = ay - by;
    float dz = az - bz;
    return (dx * dx + dy * dy) + dz * dz;
}

// Packed 2-wide exact sqdist: same op order per component, no contraction.
// Targets v_pk_add_f32 / v_pk_mul_f32 (VOP3P); falls back to 2x scalar.
__device__ __forceinline__ f32x2 sqdist2_exact(f32x2 px, f32x2 py, f32x2 pz,
                                               f32x2 cx2, f32x2 cy2, f32x2 cz2) {
#pragma clang fp contract(off)
    f32x2 dx = px - cx2;
    f32x2 dy = py - cy2;
    f32x2 dz = pz - cz2;
    return (dx * dx + dy * dy) + dz * dz;
}

// u64 max (compare-select, ~3 VALU insts, branchless)
__device__ __forceinline__ unsigned long long u64max(unsigned long long a,
                                                     unsigned long long b) {
    return (a > b) ? a : b;
}

// DPP wave-64 reduce steps (gfx9 lineage: row_shr + row_bcast legal on CDNA4).
// u64 max step via DPP (2 dpp movs + u64 cmp/select, pure VALU). Identity 0
// is safe: keys are always non-negative (dist bits in the high half).
template <int CTRL>
__device__ __forceinline__ unsigned long long dpp_u64max_step(unsigned long long k) {
    int lo = __builtin_amdgcn_update_dpp(0, (int)(unsigned)(k & 0xffffffffu),
                                         CTRL, 0xf, 0xf, false);
    int hi = __builtin_amdgcn_update_dpp(0, (int)(unsigned)(k >> 32),
                                         CTRL, 0xf, 0xf, false);
    unsigned long long o = ((unsigned long long)(unsigned)hi << 32) | (unsigned)lo;
    return (o > k) ? o : k;
}
#define ROW_SHR1 0x111
#define ROW_SHR2 0x112
#define ROW_SHR4 0x114
#define ROW_SHR8 0x118
#define ROW_BC15 0x142
#define ROW_BC31 0x143

// full-wave min/max butterfly (init-time only, not on the hot path)
__device__ __forceinline__ void wave_minmax(float x, float& lo, float& hi) {
    float a = x, b = x;
#pragma unroll
    for (int off = 1; off < 64; off <<= 1) {
        a = fminf(a, __shfl_xor(a, off));
        b = fmaxf(b, __shfl_xor(b, off));
    }
    lo = a;
    hi = b;
}

// ---------------------------------------------------------------------------
// Weight transpose prep: w1T[c][64], w2T[j][64], w3T[j][128]
// ---------------------------------------------------------------------------
__global__ void prep_kernel(const float* __restrict__ w1, const float* __restrict__ w2,
                            const float* __restrict__ w3, float* __restrict__ w1T,
                            float* __restrict__ w2T, float* __restrict__ w3T) {
    for (int i = threadIdx.x; i < 192; i += 256) {
        int oc = i / 3, c = i % 3;
        w1T[c * 64 + oc] = w1[i];
    }
    for (int i = threadIdx.x; i < 4096; i += 256) {
        int oc = i >> 6, j = i & 63;
        w2T[j * 64 + oc] = w2[i];
    }
    for (int i = threadIdx.x; i < 8192; i += 256) {
        int oc = i >> 6, j = i & 63;
        w3T[j * 128 + oc] = w3[i];
    }
}

// spread 3-bit value to bit positions 0,3,6
__device__ __forceinline__ int part3(int v) {
    return (v & 1) | ((v & 2) << 2) | ((v & 4) << 4);
}

#define PT_LIST(X) X(0) X(1) X(2) X(3) X(4) X(5) X(6) X(7) \
                   X(8) X(9) X(10) X(11) X(12) X(13) X(14) X(15)
#define PR_LIST(X) X(0) X(1) X(2) X(3) X(4) X(5) X(6) X(7)

// ---------------------------------------------------------------------------
// FPS — R18. Counter math from R17 (1719us, VALU 46% per active CU): per
// iter ~2016cy = ~930cy VALU issue per SIMD (2 waves x ~230 busy insts x 2cy)
// + ~1080cy latency/barrier stalls, well overlapped. +-40-inst tweaks were
// noise; to move, halve the ISSUE term. R18 = R17 with the update packed:
//   - pairs of bricks (2j, 2j+1) share f32x2 registers; sqdist on
//     ext_vector float2 -> v_pk_add_f32/v_pk_mul_f32 (VOP3P, 2 f32/inst).
//     IEEE per component + contract(off) -> bit-exact, same op order.
//   - update is FULLY BRANCHLESS (all 16 bricks unconditionally): the
//     unconditional min-update IS the reference semantics (trivially exact);
//     this also deletes the 16 wave-uniform guard branches (s_cbranch
//     bubbles) R13/R17 carried.
//   - wave-level skip unchanged (mask over brick lbs vs wave_bv; mask==0 ->
//     cached waveKey straight to barrier) — verified bound argument.
// Joint u64 argmax tree + single DPP chain (R17, verified), cross-wave tail,
// Morton sort, brick bboxes, one barrier/iter: all byte-identical.
// ---------------------------------------------------------------------------
__global__ __attribute__((amdgpu_flat_work_group_size(512, 512),
                          amdgpu_waves_per_eu(2, 2)))
void fps_kernel(const float* __restrict__ xyz_all,
                float4* __restrict__ wsSorted,
                float4* __restrict__ wsCtr,
                float* __restrict__ out0) {
    const int b = blockIdx.x;
    const float* xyz = xyz_all + (size_t)b * NN * 3;
    float4* sorted = wsSorted + (size_t)b * NN;
    float4* ctr = wsCtr + (size_t)b * SS;
    float* o0 = out0 + (size_t)b * 3 * SS;

    __shared__ float xLds[NN];            // 32KB
    __shared__ float yLds[NN];            // 32KB
    __shared__ float zLds[NN];            // 32KB
    __shared__ float4 ctrLds[SS];         // 32KB
    __shared__ int cellCnt[512];
    __shared__ int cellBase[512];
    __shared__ unsigned long long red[2][8];

    const int tid = threadIdx.x;
    const int wid = tid >> 6;
    const int lane = tid & 63;

    // --- pass 1: per-Morton-cell counts (16 pts/thread) + stage xyz in LDS
    cellCnt[tid] = 0;
    __syncthreads();
    int cellReg[16];
#pragma unroll
    for (int j = 0; j < 16; ++j) {
        int p = tid + j * 512;
        float x = xyz[p * 3 + 0], y = xyz[p * 3 + 1], z = xyz[p * 3 + 2];
        xLds[p] = x; yLds[p] = y; zLds[p] = z;
        int qx = min(7, (int)(x * 8.0f));
        int qy = min(7, (int)(y * 8.0f));
        int qz = min(7, (int)(z * 8.0f));
        cellReg[j] = part3(qx) | (part3(qy) << 1) | (part3(qz) << 2);
        atomicAdd(&cellCnt[cellReg[j]], 1);
    }
    __syncthreads();
    int myCnt = cellCnt[tid];
    // inclusive Hillis-Steele scan over 512 cells (thread==cell)
    for (int off = 1; off < 512; off <<= 1) {
        int v = (tid >= off) ? cellCnt[tid - off] : 0;
        __syncthreads();
        cellCnt[tid] += v;
        __syncthreads();
    }
    cellBase[tid] = cellCnt[tid] - myCnt;
    __syncthreads();
    // --- pass 2: scatter to global ws in PLAIN Morton-slot order. The reader
    // (brick i, lane l <-> slot (wid*16+i)*64 + l) is coalesced directly.
#pragma unroll
    for (int j = 0; j < 16; ++j) {
        int p = tid + j * 512;
        float x = xLds[p], y = yLds[p], z = zLds[p];
        int pos = atomicAdd(&cellBase[cellReg[j]], 1);
        sorted[pos] = make_float4(x, y, z, __int_as_float(p));
    }
    __threadfence();
    __syncthreads();

    // --- load 16 bricks as 8 packed pairs: pair j holds bricks 2j (.x) and
    // 2j+1 (.y); lane l owns slot (wid*16+brick)*64 + l of each.
    // ndA/ndB = ~original_index for key packing.
#define DECL_PR(j)                                                   \
    f32x2 px##j, py##j, pz##j, dist##j;                              \
    int ndA##j, ndB##j;                                              \
    {                                                                \
        float4 va = sorted[(wid * 16 + 2 * j) * 64 + lane];          \
        float4 vb = sorted[(wid * 16 + 2 * j + 1) * 64 + lane];      \
        px##j = (f32x2){va.x, vb.x};                                 \
        py##j = (f32x2){va.y, vb.y};                                 \
        pz##j = (f32x2){va.z, vb.z};                                 \
        ndA##j = ~__float_as_int(va.w);                              \
        ndB##j = ~__float_as_int(vb.w);                              \
        dist##j = (f32x2){1e10f, 1e10f};                             \
    }
    PR_LIST(DECL_PR)

    // --- brick bboxes: brick 2j from pair j component x, brick 2j+1 from y.
    // Computed via shfl butterflies (one-time); lane i keeps brick i's bbox.
    float bbxlo = 0.f, bbxhi = 0.f, bbylo = 0.f, bbyhi = 0.f,
          bbzlo = 0.f, bbzhi = 0.f;
#define BRICK_BB2(j)                                              \
    {                                                             \
        float xl, xh, yl, yh, zl, zh;                             \
        wave_minmax(px##j.x, xl, xh);                             \
        wave_minmax(py##j.x, yl, yh);                             \
        wave_minmax(pz##j.x, zl, zh);                             \
        if (lane == 2 * j) {                                      \
            bbxlo = xl; bbxhi = xh;                               \
            bbylo = yl; bbyhi = yh;                               \
            bbzlo = zl; bbzhi = zh;                               \
        }                                                         \
        wave_minmax(px##j.y, xl, xh);                             \
        wave_minmax(py##j.y, yl, yh);                             \
        wave_minmax(pz##j.y, zl, zh);                             \
        if (lane == 2 * j + 1) {                                  \
            bbxlo = xl; bbxhi = xh;                               \
            bbylo = yl; bbyhi = yh;                               \
            bbzlo = zl; bbzhi = zh;                               \
        }                                                         \
    }
    PR_LIST(BRICK_BB2)

    float cx = xLds[0], cy = yLds[0], cz = zLds[0];
    if (tid == 0) ctrLds[0] = make_float4(cx, cy, cz, 0.0f);

    unsigned long long waveKey =
        ((unsigned long long)__float_as_uint(1e10f) << 32) | 0xFFFFFFFFull;
    float wave_bv = 1e10f;  // max min-dist over this wave's 1024 points (cached)

    for (int s = 1; s < SS; ++s) {
        const int par = s & 1;
        // brick-granular prune vs wave_bv: lane i<16 tests brick i's lower
        // bound; mask==0 -> whole wave provably unchanged (exact skip).
        float ddx = fmaxf(fmaxf(bbxlo - cx, cx - bbxhi), 0.0f);
        float ddy = fmaxf(fmaxf(bbylo - cy, cy - bbyhi), 0.0f);
        float ddz = fmaxf(fmaxf(bbzlo - cz, cz - bbzhi), 0.0f);
        float lb2 = (ddx * ddx + ddy * ddy) + ddz * ddz;
        bool act = (lane < 16) && (lb2 * 0.999f < wave_bv);
        if (__ballot(act)) {
            // branchless packed full update (reference semantics: min over
            // every point, every iteration — trivially exact)
            const f32x2 c2x = (f32x2){cx, cx};
            const f32x2 c2y = (f32x2){cy, cy};
            const f32x2 c2z = (f32x2){cz, cz};
#define UPD_PR(j)                                                        \
    {                                                                    \
        f32x2 d = sqdist2_exact(px##j, py##j, pz##j, c2x, c2y, c2z);     \
        dist##j.x = fminf(dist##j.x, d.x);                               \
        dist##j.y = fminf(dist##j.y, d.y);                               \
    }
            PR_LIST(UPD_PR)
            // joint u64 argmax over all 16 bricks:
            // key = (dist bits << 32) | ~od
#define KEY_PR(j)                                                        \
    unsigned long long kA##j =                                           \
        ((unsigned long long)__float_as_uint(dist##j.x) << 32) |         \
        (unsigned)ndA##j;                                                \
    unsigned long long kB##j =                                           \
        ((unsigned long long)__float_as_uint(dist##j.y) << 32) |         \
        (unsigned)ndB##j;
            PR_LIST(KEY_PR)
            // 4-level ILP tree over the 16 per-lane keys
            unsigned long long t0 = u64max(kA0, kB0), t1 = u64max(kA1, kB1),
                               t2 = u64max(kA2, kB2), t3 = u64max(kA3, kB3),
                               t4 = u64max(kA4, kB4), t5 = u64max(kA5, kB5),
                               t6 = u64max(kA6, kB6), t7 = u64max(kA7, kB7);
            unsigned long long u0 = u64max(t0, t1), u1 = u64max(t2, t3),
                               u2 = u64max(t4, t5), u3 = u64max(t6, t7);
            unsigned long long K = u64max(u64max(u0, u1), u64max(u2, u3));
            // cross-lane: ONE 6-step DPP u64max chain -> lane 63 writes red
            K = dpp_u64max_step<ROW_SHR1>(K);
            K = dpp_u64max_step<ROW_SHR2>(K);
            K = dpp_u64max_step<ROW_SHR4>(K);
            K = dpp_u64max_step<ROW_SHR8>(K);
            K = dpp_u64max_step<ROW_BC15>(K);
            K = dpp_u64max_step<ROW_BC31>(K);
            if (lane == 63) red[par][wid] = K;
            // refresh cached wave key + wave_bv (for future quiet iters)
            unsigned wlo = (unsigned)__builtin_amdgcn_readlane(
                (int)(unsigned)(K & 0xffffffffu), 63);
            unsigned whi = (unsigned)__builtin_amdgcn_readlane(
                (int)(unsigned)(K >> 32), 63);
            waveKey = ((unsigned long long)whi << 32) | wlo;
            wave_bv = __int_as_float((int)whi);
        } else {
            if (lane == 0) red[par][wid] = waveKey;
        }
        __syncthreads();  // lgkm-only drain (no global ops in loop)
        // cross-wave reduce: ONE lane-indexed b64 read + 3 DPP row_shr u64-max
        // steps (lane 7 of each 16-row = max over slots 0..7); the winning
        // index is the low half of the max key -> one readlane, no ballot.
        unsigned long long k = red[par][lane & 7];
        k = dpp_u64max_step<ROW_SHR1>(k);
        k = dpp_u64max_step<ROW_SHR2>(k);
        k = dpp_u64max_step<ROW_SHR4>(k);
        unsigned blo = (unsigned)__builtin_amdgcn_readlane(
            (int)(unsigned)(k & 0xffffffffu), 7);
        int wiu = (int)(~blo);  // uniform (SGPR) winner index
        cx = xLds[wiu];  // 3 independent broadcast ds_read_b32
        cy = yLds[wiu];
        cz = zLds[wiu];
        if (tid == 0) ctrLds[s] = make_float4(cx, cy, cz, 0.0f);
    }

    // --- single coalesced write-out of all centers
    __syncthreads();
    for (int s = tid; s < SS; s += 512) {
        float4 c = ctrLds[s];
        o0[s] = c.x;
        o0[SS + s] = c.y;
        o0[2 * SS + s] = c.z;
        ctr[s] = c;
    }
}

// ---------------------------------------------------------------------------
// Fused ball-query + MLP + maxpool. Block = 128 threads (2 waves), 2 centers.
// LDS halved (R9): h2 reuses h1's buffer in place -> ~17KB -> ~9 blocks/CU.
// ---------------------------------------------------------------------------
__global__ __launch_bounds__(128) void bqmlp_kernel(const float* __restrict__ xyz_all,
                                                    const float4* __restrict__ wsCtr,
                                                    const float* __restrict__ w1T,
                                                    const float* __restrict__ b1,
                                                    const float* __restrict__ w2T,
                                                    const float* __restrict__ b2,
                                                    const float* __restrict__ w3T,
                                                    const float* __restrict__ b3,
                                                    float* __restrict__ out1) {
    const int b = blockIdx.x >> 10;            // 1024 blocks per batch
    const int s0 = (blockIdx.x & 1023) * 2;    // 2 centers per block
    const float* xyz = xyz_all + (size_t)b * NN * 3;

    __shared__ float relF[2 * KNB * 3];  // [64 rows][3]
    __shared__ float hT[64 * 64];        // [ch][row] — holds h1, then h2

    const int tid = threadIdx.x;
    const int cb = __builtin_amdgcn_readfirstlane(tid >> 6);  // wave id (uniform)
    const int l = tid & 63;

    // ---- ball query: wave cb handles center s0+cb
    {
        float4 cc = wsCtr[(size_t)b * SS + s0 + cb];
        float ccx = cc.x, ccy = cc.y, ccz = cc.z;
        const float R2 = (float)(0.2 * 0.2);
        int total = 0;
        float fx = 0.f, fy = 0.f, fz = 0.f;
        bool have = false;
        for (int chunk = 0; chunk < 128 && total < KNB; ++chunk) {
            int p = chunk * 64 + l;
            float x = xyz[p * 3 + 0], y = xyz[p * 3 + 1], z = xyz[p * 3 + 2];
            float d = sqdist_exact(ccx, ccy, ccz, x, y, z);
            bool hit = (d <= R2);
            unsigned long long mask = __ballot(hit);
            int cnt = __popcll(mask);
            if (cnt) {
                int pos = total + __popcll(mask & ((1ull << l) - 1ull));
                float rx = x - ccx, ry = y - ccy, rz = z - ccz;  // single subs: exact
                if (hit && pos < KNB) {
                    relF[(cb * KNB + pos) * 3 + 0] = rx;
                    relF[(cb * KNB + pos) * 3 + 1] = ry;
                    relF[(cb * KNB + pos) * 3 + 2] = rz;
                }
                if (hit && pos == 0) { fx = rx; fy = ry; fz = rz; have = true; }
                total += cnt;
            }
        }
        unsigned long long hm = __ballot(have);
        if (total < KNB) {
            int src = __ffsll((long long)hm) - 1;
            float gx = __shfl(fx, src), gy = __shfl(fy, src), gz = __shfl(fz, src);
            if (l >= total && l < KNB) {
                relF[(cb * KNB + l) * 3 + 0] = gx;
                relF[(cb * KNB + l) * 3 + 1] = gy;
                relF[(cb * KNB + l) * 3 + 2] = gz;
            }
        }
    }
    __syncthreads();

    const int r = l;  // row 0..63: rows 0..31 center s0, rows 32..63 center s0+1

    // ---- layer 1: rel(3) -> 64, thread covers ch block cb*32..+31 for row r
    {
        float rx = relF[r * 3 + 0], ry = relF[r * 3 + 1], rz = relF[r * 3 + 2];
#pragma unroll
        for (int i = 0; i < 32; ++i) {
            int ch = cb * 32 + i;
            float h = b1[ch];
            h = fmaf(rx, w1T[0 * 64 + ch], h);
            h = fmaf(ry, w1T[1 * 64 + ch], h);
            h = fmaf(rz, w1T[2 * 64 + ch], h);
            hT[ch * 64 + r] = fmaxf(h, 0.0f);
        }
    }
    __syncthreads();

    // ---- layer 2: 64 -> 64 (reads h1 from hT; after barrier, h2 overwrites)
    {
        float acc[32];
#pragma unroll
        for (int i = 0; i < 32; ++i) acc[i] = b2[cb * 32 + i];
#pragma unroll 4
        for (int j = 0; j < 64; ++j) {
            float a = hT[j * 64 + r];
            const float* wrow = w2T + j * 64 + cb * 32;
#pragma unroll
            for (int i = 0; i < 32; ++i) acc[i] = fmaf(a, wrow[i], acc[i]);
        }
        __syncthreads();  // all h1 reads complete before overwrite
#pragma unroll
        for (int i = 0; i < 32; ++i) hT[(cb * 32 + i) * 64 + r] = fmaxf(acc[i], 0.0f);
    }
    __syncthreads();

    // ---- layer 3: 64 -> 128, fused relu + maxpool over the 32 rows/center
    {
        float acc[64];
#pragma unroll
        for (int i = 0; i < 64; ++i) acc[i] = b3[cb * 64 + i];
#pragma unroll 2
        for (int j = 0; j < 64; ++j) {
            float a = hT[j * 64 + r];
            const float* wrow = w3T + j * 128 + cb * 64;
#pragma unroll
            for (int i = 0; i < 64; ++i) acc[i] = fmaf(a, wrow[i], acc[i]);
        }
#pragma unroll
        for (int i = 0; i < 64; ++i) {
            float v = fmaxf(acc[i], 0.0f);
            v = fmaxf(v, __shfl_xor(v, 1));
            v = fmaxf(v, __shfl_xor(v, 2));
            v = fmaxf(v, __shfl_xor(v, 4));
            v = fmaxf(v, __shfl_xor(v, 8));
            v = fmaxf(v, __shfl_xor(v, 16));
            acc[i] = v;
        }
        if ((l & 31) == 0) {
            int sA = s0 + (l >> 5);
            float* op = out1 + ((size_t)b * 128 + cb * 64) * SS + sA;
#pragma unroll
            for (int i = 0; i < 64; ++i) op[(size_t)i * SS] = acc[i];
        }
    }
}

extern "C" void kernel_launch(void* const* d_in, const int* in_sizes, int n_in,
                              void* d_out, int out_size, void* d_ws, size_t ws_size,
                              hipStream_t stream) {
    (void)in_sizes; (void)n_in; (void)out_size; (void)ws_size;
    const float* xyz = (const float*)d_in[0];
    // d_in[1] = features : unused by the reference
    const float* w1 = (const float*)d_in[2];
    const float* b1 = (const float*)d_in[3];
    const float* w2 = (const float*)d_in[4];
    const float* b2 = (const float*)d_in[5];
    const float* w3 = (const float*)d_in[6];
    const float* b3 = (const float*)d_in[7];
    float* out = (float*)d_out;

    // workspace layout
    float4* wsCtr = (float4*)d_ws;              // B*S float4      (256 KB)
    float4* wsSorted = wsCtr + BB * SS;         // B*N float4      (1 MB)
    float* w1T = (float*)(wsSorted + BB * NN);  // 192 f
    float* w2T = w1T + 192;                     // 4096 f
    float* w3T = w2T + 4096;                    // 8192 f

    prep_kernel<<<1, 256, 0, stream>>>(w1, w2, w3, w1T, w2T, w3T);
    fps_kernel<<<BB, 512, 0, stream>>>(xyz, wsSorted, wsCtr, out);
    bqmlp_kernel<<<BB * (SS / 2), 128, 0, stream>>>(xyz, wsCtr, w1T, b1, w2T, b2,
                                                    w3T, b3, out + BB * 3 * SS);
}

// Round 8
// 1884.080 us; speedup vs baseline: 1.3584x; 1.0342x over previous
//
#include <hip/hip_runtime.h>
#include <cstdint>
#include <cstddef>

#define BB 8
#define NN 8192
#define SS 2048
#define KNB 32

typedef float f32x2 __attribute__((ext_vector_type(2)));

// Bit-exact squared distance matching numpy: (a-b) per component, squares,
// left-to-right sum, no FMA contraction.
__device__ __forceinline__ float sqdist_exact(float ax, float ay, float az,
                                              float bx, float by, float bz) {
#pragma clang fp contract(off)
    float dx = ax - bx;
    float dy = ay - by;
    float dz = az - bz;
    return (dx * dx + dy * dy) + dz * dz;
}

// Packed 2-wide exact sqdist: same op order per component, no contraction.
// Targets v_pk_add_f32 / v_pk_mul_f32 (VOP3P); falls back to 2x scalar.
__device__ __forceinline__ f32x2 sqdist2_exact(f32x2 px, f32x2 py, f32x2 pz,
                                               f32x2 cx2, f32x2 cy2, f32x2 cz2) {
#pragma clang fp contract(off)
    f32x2 dx = px - cx2;
    f32x2 dy = py - cy2;
    f32x2 dz = pz - cz2;
    return (dx * dx + dy * dy) + dz * dz;
}

// u64 max (compare-select, ~3 VALU insts, branchless)
__device__ __forceinline__ unsigned long long u64max(unsigned long long a,
                                                     unsigned long long b) {
    return (a > b) ? a : b;
}

// DPP wave-64 reduce steps (gfx9 lineage: row_shr + row_bcast legal on CDNA4).
// u64 max step via DPP (2 dpp movs + u64 cmp/select, pure VALU). Identity 0
// is safe: keys are always non-negative (dist bits in the high half).
template <int CTRL>
__device__ __forceinline__ unsigned long long dpp_u64max_step(unsigned long long k) {
    int lo = __builtin_amdgcn_update_dpp(0, (int)(unsigned)(k & 0xffffffffu),
                                         CTRL, 0xf, 0xf, false);
    int hi = __builtin_amdgcn_update_dpp(0, (int)(unsigned)(k >> 32),
                                         CTRL, 0xf, 0xf, false);
    unsigned long long o = ((unsigned long long)(unsigned)hi << 32) | (unsigned)lo;
    return (o > k) ? o : k;
}
#define ROW_SHR1 0x111
#define ROW_SHR2 0x112
#define ROW_SHR4 0x114
#define ROW_SHR8 0x118
#define ROW_BC15 0x142
#define ROW_BC31 0x143

// full-wave min/max butterfly (init-time only, not on the hot path)
__device__ __forceinline__ void wave_minmax(float x, float& lo, float& hi) {
    float a = x, b = x;
#pragma unroll
    for (int off = 1; off < 64; off <<= 1) {
        a = fminf(a, __shfl_xor(a, off));
        b = fmaxf(b, __shfl_xor(b, off));
    }
    lo = a;
    hi = b;
}

// ---------------------------------------------------------------------------
// Weight transpose prep: w1T[c][64], w2T[j][64], w3T[j][128]
// ---------------------------------------------------------------------------
__global__ void prep_kernel(const float* __restrict__ w1, const float* __restrict__ w2,
                            const float* __restrict__ w3, float* __restrict__ w1T,
                            float* __restrict__ w2T, float* __restrict__ w3T) {
    for (int i = threadIdx.x; i < 192; i += 256) {
        int oc = i / 3, c = i % 3;
        w1T[c * 64 + oc] = w1[i];
    }
    for (int i = threadIdx.x; i < 4096; i += 256) {
        int oc = i >> 6, j = i & 63;
        w2T[j * 64 + oc] = w2[i];
    }
    for (int i = threadIdx.x; i < 8192; i += 256) {
        int oc = i >> 6, j = i & 63;
        w3T[j * 128 + oc] = w3[i];
    }
}

// spread 3-bit value to bit positions 0,3,6
__device__ __forceinline__ int part3(int v) {
    return (v & 1) | ((v & 2) << 2) | ((v & 4) << 4);
}

#define P4_LIST(X) X(0) X(1) X(2) X(3)

// ---------------------------------------------------------------------------
// FPS — R19. R18 (1624us, best) showed 55% per-CU VALU busy: ~half issue,
// ~half unhidden latency with only 2 waves/SIMD. Issue per SIMD is fixed by
// the point count; the latency-hiding factor is WAVES PER SIMD. R19 = R18's
// exact algorithm re-tiled to 1024 threads / 16 waves (4 waves/SIMD):
//   - wave owns 512 Morton slots = 8 bricks of 64; 8 pts/thread as 4 packed
//     f32x2 pairs. Busy path per wave halves (~125 insts, tree depth 3);
//     4 independent streams/SIMD interleave over every DPP/LDS stall.
//   - brick bboxes in lanes 0..7; prune lane<8 vs wave_bv (same exact-skip
//     bound argument); packed branchless update (reference semantics).
//   - red[2][16]; cross-wave tail: one lane-indexed b64 read + 4 DPP
//     row_shr steps (lane 15 = max over 16 slots) + readlane(15).
//   - pass-1 histogram/scan guarded for 512 cells with 1024 threads.
// VGPR ~60-70 < 128 so 4 waves/SIMD fits (waves_per_eu(4,4)). Morton sort,
// joint u64 argmax semantics (max dist, tie -> min orig index via ~od),
// one barrier/iter parity buffer, bqmlp: all unchanged (verified R18).
// ---------------------------------------------------------------------------
__global__ __attribute__((amdgpu_flat_work_group_size(1024, 1024),
                          amdgpu_waves_per_eu(4, 4)))
void fps_kernel(const float* __restrict__ xyz_all,
                float4* __restrict__ wsSorted,
                float4* __restrict__ wsCtr,
                float* __restrict__ out0) {
    const int b = blockIdx.x;
    const float* xyz = xyz_all + (size_t)b * NN * 3;
    float4* sorted = wsSorted + (size_t)b * NN;
    float4* ctr = wsCtr + (size_t)b * SS;
    float* o0 = out0 + (size_t)b * 3 * SS;

    __shared__ float xLds[NN];            // 32KB
    __shared__ float yLds[NN];            // 32KB
    __shared__ float zLds[NN];            // 32KB
    __shared__ float4 ctrLds[SS];         // 32KB
    __shared__ int cellCnt[512];
    __shared__ int cellBase[512];
    __shared__ unsigned long long red[2][16];

    const int tid = threadIdx.x;
    const int wid = tid >> 6;
    const int lane = tid & 63;

    // --- pass 1: per-Morton-cell counts (8 pts/thread) + stage xyz in LDS
    if (tid < 512) cellCnt[tid] = 0;
    __syncthreads();
    int cellReg[8];
#pragma unroll
    for (int j = 0; j < 8; ++j) {
        int p = tid + j * 1024;
        float x = xyz[p * 3 + 0], y = xyz[p * 3 + 1], z = xyz[p * 3 + 2];
        xLds[p] = x; yLds[p] = y; zLds[p] = z;
        int qx = min(7, (int)(x * 8.0f));
        int qy = min(7, (int)(y * 8.0f));
        int qz = min(7, (int)(z * 8.0f));
        cellReg[j] = part3(qx) | (part3(qy) << 1) | (part3(qz) << 2);
        atomicAdd(&cellCnt[cellReg[j]], 1);
    }
    __syncthreads();
    int myCnt = (tid < 512) ? cellCnt[tid] : 0;
    // inclusive Hillis-Steele scan over 512 cells (threads 0..511)
    for (int off = 1; off < 512; off <<= 1) {
        int v = (tid < 512 && tid >= off) ? cellCnt[tid - off] : 0;
        __syncthreads();
        if (tid < 512) cellCnt[tid] += v;
        __syncthreads();
    }
    if (tid < 512) cellBase[tid] = cellCnt[tid] - myCnt;
    __syncthreads();
    // --- pass 2: scatter to global ws in PLAIN Morton-slot order. The reader
    // (brick i, lane l <-> slot (wid*8+i)*64 + l) is coalesced directly.
#pragma unroll
    for (int j = 0; j < 8; ++j) {
        int p = tid + j * 1024;
        float x = xLds[p], y = yLds[p], z = zLds[p];
        int pos = atomicAdd(&cellBase[cellReg[j]], 1);
        sorted[pos] = make_float4(x, y, z, __int_as_float(p));
    }
    __threadfence();
    __syncthreads();

    // --- load 8 bricks as 4 packed pairs: pair j holds bricks wid*8+2j (.x)
    // and wid*8+2j+1 (.y); lane l owns slot (brick)*64 + l of each.
#define DECL_PR(j)                                                   \
    f32x2 px##j, py##j, pz##j, dist##j;                              \
    int ndA##j, ndB##j;                                              \
    {                                                                \
        float4 va = sorted[(wid * 8 + 2 * j) * 64 + lane];           \
        float4 vb = sorted[(wid * 8 + 2 * j + 1) * 64 + lane];       \
        px##j = (f32x2){va.x, vb.x};                                 \
        py##j = (f32x2){va.y, vb.y};                                 \
        pz##j = (f32x2){va.z, vb.z};                                 \
        ndA##j = ~__float_as_int(va.w);                              \
        ndB##j = ~__float_as_int(vb.w);                              \
        dist##j = (f32x2){1e10f, 1e10f};                             \
    }
    P4_LIST(DECL_PR)

    // --- brick bboxes: brick 2j from pair j component x, brick 2j+1 from y.
    // Computed via shfl butterflies (one-time); lane i (<8) keeps brick i's.
    float bbxlo = 0.f, bbxhi = 0.f, bbylo = 0.f, bbyhi = 0.f,
          bbzlo = 0.f, bbzhi = 0.f;
#define BRICK_BB2(j)                                              \
    {                                                             \
        float xl, xh, yl, yh, zl, zh;                             \
        wave_minmax(px##j.x, xl, xh);                             \
        wave_minmax(py##j.x, yl, yh);                             \
        wave_minmax(pz##j.x, zl, zh);                             \
        if (lane == 2 * j) {                                      \
            bbxlo = xl; bbxhi = xh;                               \
            bbylo = yl; bbyhi = yh;                               \
            bbzlo = zl; bbzhi = zh;                               \
        }                                                         \
        wave_minmax(px##j.y, xl, xh);                             \
        wave_minmax(py##j.y, yl, yh);                             \
        wave_minmax(pz##j.y, zl, zh);                             \
        if (lane == 2 * j + 1) {                                  \
            bbxlo = xl; bbxhi = xh;                               \
            bbylo = yl; bbyhi = yh;                               \
            bbzlo = zl; bbzhi = zh;                               \
        }                                                         \
    }
    P4_LIST(BRICK_BB2)

    float cx = xLds[0], cy = yLds[0], cz = zLds[0];
    if (tid == 0) ctrLds[0] = make_float4(cx, cy, cz, 0.0f);

    unsigned long long waveKey =
        ((unsigned long long)__float_as_uint(1e10f) << 32) | 0xFFFFFFFFull;
    float wave_bv = 1e10f;  // max min-dist over this wave's 512 points (cached)

    for (int s = 1; s < SS; ++s) {
        const int par = s & 1;
        // brick-granular prune vs wave_bv: lane i<8 tests brick i's lower
        // bound; all-clear -> whole wave provably unchanged (exact skip).
        float ddx = fmaxf(fmaxf(bbxlo - cx, cx - bbxhi), 0.0f);
        float ddy = fmaxf(fmaxf(bbylo - cy, cy - bbyhi), 0.0f);
        float ddz = fmaxf(fmaxf(bbzlo - cz, cz - bbzhi), 0.0f);
        float lb2 = (ddx * ddx + ddy * ddy) + ddz * ddz;
        bool act = (lane < 8) && (lb2 * 0.999f < wave_bv);
        if (__ballot(act)) {
            // branchless packed full update (reference semantics: min over
            // every point, every iteration — trivially exact)
            const f32x2 c2x = (f32x2){cx, cx};
            const f32x2 c2y = (f32x2){cy, cy};
            const f32x2 c2z = (f32x2){cz, cz};
#define UPD_PR(j)                                                        \
    {                                                                    \
        f32x2 d = sqdist2_exact(px##j, py##j, pz##j, c2x, c2y, c2z);     \
        dist##j.x = fminf(dist##j.x, d.x);                               \
        dist##j.y = fminf(dist##j.y, d.y);                               \
    }
            P4_LIST(UPD_PR)
            // joint u64 argmax over the 8 bricks: key = (dist<<32) | ~od
#define KEY_PR(j)                                                        \
    unsigned long long kA##j =                                           \
        ((unsigned long long)__float_as_uint(dist##j.x) << 32) |         \
        (unsigned)ndA##j;                                                \
    unsigned long long kB##j =                                           \
        ((unsigned long long)__float_as_uint(dist##j.y) << 32) |         \
        (unsigned)ndB##j;
            P4_LIST(KEY_PR)
            // 3-level ILP tree over the 8 per-lane keys
            unsigned long long t0 = u64max(kA0, kB0), t1 = u64max(kA1, kB1),
                               t2 = u64max(kA2, kB2), t3 = u64max(kA3, kB3);
            unsigned long long K = u64max(u64max(t0, t1), u64max(t2, t3));
            // cross-lane: ONE 6-step DPP u64max chain -> lane 63 writes red
            K = dpp_u64max_step<ROW_SHR1>(K);
            K = dpp_u64max_step<ROW_SHR2>(K);
            K = dpp_u64max_step<ROW_SHR4>(K);
            K = dpp_u64max_step<ROW_SHR8>(K);
            K = dpp_u64max_step<ROW_BC15>(K);
            K = dpp_u64max_step<ROW_BC31>(K);
            if (lane == 63) red[par][wid] = K;
            // refresh cached wave key + wave_bv (for future quiet iters)
            unsigned wlo = (unsigned)__builtin_amdgcn_readlane(
                (int)(unsigned)(K & 0xffffffffu), 63);
            unsigned whi = (unsigned)__builtin_amdgcn_readlane(
                (int)(unsigned)(K >> 32), 63);
            waveKey = ((unsigned long long)whi << 32) | wlo;
            wave_bv = __int_as_float((int)whi);
        } else {
            if (lane == 0) red[par][wid] = waveKey;
        }
        __syncthreads();  // lgkm-only drain (no global ops in loop)
        // cross-wave reduce: ONE lane-indexed b64 read + 4 DPP row_shr u64-max
        // steps (lane 15 = max over slots 0..15); the winning index is the
        // low half of the max key -> one readlane, no ballot.
        unsigned long long k = red[par][lane & 15];
        k = dpp_u64max_step<ROW_SHR1>(k);
        k = dpp_u64max_step<ROW_SHR2>(k);
        k = dpp_u64max_step<ROW_SHR4>(k);
        k = dpp_u64max_step<ROW_SHR8>(k);
        unsigned blo = (unsigned)__builtin_amdgcn_readlane(
            (int)(unsigned)(k & 0xffffffffu), 15);
        int wiu = (int)(~blo);  // uniform (SGPR) winner index
        cx = xLds[wiu];  // 3 independent broadcast ds_read_b32
        cy = yLds[wiu];
        cz = zLds[wiu];
        if (tid == 0) ctrLds[s] = make_float4(cx, cy, cz, 0.0f);
    }

    // --- single coalesced write-out of all centers
    __syncthreads();
    for (int s = tid; s < SS; s += 1024) {
        float4 c = ctrLds[s];
        o0[s] = c.x;
        o0[SS + s] = c.y;
        o0[2 * SS + s] = c.z;
        ctr[s] = c;
    }
}

// ---------------------------------------------------------------------------
// Fused ball-query + MLP + maxpool. Block = 128 threads (2 waves), 2 centers.
// LDS halved (R9): h2 reuses h1's buffer in place -> ~17KB -> ~9 blocks/CU.
// ---------------------------------------------------------------------------
__global__ __launch_bounds__(128) void bqmlp_kernel(const float* __restrict__ xyz_all,
                                                    const float4* __restrict__ wsCtr,
                                                    const float* __restrict__ w1T,
                                                    const float* __restrict__ b1,
                                                    const float* __restrict__ w2T,
                                                    const float* __restrict__ b2,
                                                    const float* __restrict__ w3T,
                                                    const float* __restrict__ b3,
                                                    float* __restrict__ out1) {
    const int b = blockIdx.x >> 10;            // 1024 blocks per batch
    const int s0 = (blockIdx.x & 1023) * 2;    // 2 centers per block
    const float* xyz = xyz_all + (size_t)b * NN * 3;

    __shared__ float relF[2 * KNB * 3];  // [64 rows][3]
    __shared__ float hT[64 * 64];        // [ch][row] — holds h1, then h2

    const int tid = threadIdx.x;
    const int cb = __builtin_amdgcn_readfirstlane(tid >> 6);  // wave id (uniform)
    const int l = tid & 63;

    // ---- ball query: wave cb handles center s0+cb
    {
        float4 cc = wsCtr[(size_t)b * SS + s0 + cb];
        float ccx = cc.x, ccy = cc.y, ccz = cc.z;
        const float R2 = (float)(0.2 * 0.2);
        int total = 0;
        float fx = 0.f, fy = 0.f, fz = 0.f;
        bool have = false;
        for (int chunk = 0; chunk < 128 && total < KNB; ++chunk) {
            int p = chunk * 64 + l;
            float x = xyz[p * 3 + 0], y = xyz[p * 3 + 1], z = xyz[p * 3 + 2];
            float d = sqdist_exact(ccx, ccy, ccz, x, y, z);
            bool hit = (d <= R2);
            unsigned long long mask = __ballot(hit);
            int cnt = __popcll(mask);
            if (cnt) {
                int pos = total + __popcll(mask & ((1ull << l) - 1ull));
                float rx = x - ccx, ry = y - ccy, rz = z - ccz;  // single subs: exact
                if (hit && pos < KNB) {
                    relF[(cb * KNB + pos) * 3 + 0] = rx;
                    relF[(cb * KNB + pos) * 3 + 1] = ry;
                    relF[(cb * KNB + pos) * 3 + 2] = rz;
                }
                if (hit && pos == 0) { fx = rx; fy = ry; fz = rz; have = true; }
                total += cnt;
            }
        }
        unsigned long long hm = __ballot(have);
        if (total < KNB) {
            int src = __ffsll((long long)hm) - 1;
            float gx = __shfl(fx, src), gy = __shfl(fy, src), gz = __shfl(fz, src);
            if (l >= total && l < KNB) {
                relF[(cb * KNB + l) * 3 + 0] = gx;
                relF[(cb * KNB + l) * 3 + 1] = gy;
                relF[(cb * KNB + l) * 3 + 2] = gz;
            }
        }
    }
    __syncthreads();

    const int r = l;  // row 0..63: rows 0..31 center s0, rows 32..63 center s0+1

    // ---- layer 1: rel(3) -> 64, thread covers ch block cb*32..+31 for row r
    {
        float rx = relF[r * 3 + 0], ry = relF[r * 3 + 1], rz = relF[r * 3 + 2];
#pragma unroll
        for (int i = 0; i < 32; ++i) {
            int ch = cb * 32 + i;
            float h = b1[ch];
            h = fmaf(rx, w1T[0 * 64 + ch], h);
            h = fmaf(ry, w1T[1 * 64 + ch], h);
            h = fmaf(rz, w1T[2 * 64 + ch], h);
            hT[ch * 64 + r] = fmaxf(h, 0.0f);
        }
    }
    __syncthreads();

    // ---- layer 2: 64 -> 64 (reads h1 from hT; after barrier, h2 overwrites)
    {
        float acc[32];
#pragma unroll
        for (int i = 0; i < 32; ++i) acc[i] = b2[cb * 32 + i];
#pragma unroll 4
        for (int j = 0; j < 64; ++j) {
            float a = hT[j * 64 + r];
            const float* wrow = w2T + j * 64 + cb * 32;
#pragma unroll
            for (int i = 0; i < 32; ++i) acc[i] = fmaf(a, wrow[i], acc[i]);
        }
        __syncthreads();  // all h1 reads complete before overwrite
#pragma unroll
        for (int i = 0; i < 32; ++i) hT[(cb * 32 + i) * 64 + r] = fmaxf(acc[i], 0.0f);
    }
    __syncthreads();

    // ---- layer 3: 64 -> 128, fused relu + maxpool over the 32 rows/center
    {
        float acc[64];
#pragma unroll
        for (int i = 0; i < 64; ++i) acc[i] = b3[cb * 64 + i];
#pragma unroll 2
        for (int j = 0; j < 64; ++j) {
            float a = hT[j * 64 + r];
            const float* wrow = w3T + j * 128 + cb * 64;
#pragma unroll
            for (int i = 0; i < 64; ++i) acc[i] = fmaf(a, wrow[i], acc[i]);
        }
#pragma unroll
        for (int i = 0; i < 64; ++i) {
            float v = fmaxf(acc[i], 0.0f);
            v = fmaxf(v, __shfl_xor(v, 1));
            v = fmaxf(v, __shfl_xor(v, 2));
            v = fmaxf(v, __shfl_xor(v, 4));
            v = fmaxf(v, __shfl_xor(v, 8));
            v = fmaxf(v, __shfl_xor(v, 16));
            acc[i] = v;
        }
        if ((l & 31) == 0) {
            int sA = s0 + (l >> 5);
            float* op = out1 + ((size_t)b * 128 + cb * 64) * SS + sA;
#pragma unroll
            for (int i = 0; i < 64; ++i) op[(size_t)i * SS] = acc[i];
        }
    }
}

extern "C" void kernel_launch(void* const* d_in, const int* in_sizes, int n_in,
                              void* d_out, int out_size, void* d_ws, size_t ws_size,
                              hipStream_t stream) {
    (void)in_sizes; (void)n_in; (void)out_size; (void)ws_size;
    const float* xyz = (const float*)d_in[0];
    // d_in[1] = features : unused by the reference
    const float* w1 = (const float*)d_in[2];
    const float* b1 = (const float*)d_in[3];
    const float* w2 = (const float*)d_in[4];
    const float* b2 = (const float*)d_in[5];
    const float* w3 = (const float*)d_in[6];
    const float* b3 = (const float*)d_in[7];
    float* out = (float*)d_out;

    // workspace layout
    float4* wsCtr = (float4*)d_ws;              // B*S float4      (256 KB)
    float4* wsSorted = wsCtr + BB * SS;         // B*N float4      (1 MB)
    float* w1T = (float*)(wsSorted + BB * NN);  // 192 f
    float* w2T = w1T + 192;                     // 4096 f
    float* w3T = w2T + 4096;                    // 8192 f

    prep_kernel<<<1, 256, 0, stream>>>(w1, w2, w3, w1T, w2T, w3T);
    fps_kernel<<<BB, 1024, 0, stream>>>(xyz, wsSorted, wsCtr, out);
    bqmlp_kernel<<<BB * (SS / 2), 128, 0, stream>>>(xyz, wsCtr, w1T, b1, w2T, b2,
                                                    w3T, b3, out + BB * 3 * SS);
}

// Round 10
// 1882.190 us; speedup vs baseline: 1.3597x; 1.0010x over previous
//
#include <hip/hip_runtime.h>
#include <cstdint>
#include <cstddef>

#define BB 8
#define NN 8192
#define SS 2048
#define KNB 32

typedef float f32x2 __attribute__((ext_vector_type(2)));

// Bit-exact squared distance matching numpy: (a-b) per component, squares,
// left-to-right sum, no FMA contraction.
__device__ __forceinline__ float sqdist_exact(float ax, float ay, float az,
                                              float bx, float by, float bz) {
#pragma clang fp contract(off)
    float dx = ax - bx;
    float dy = ay - by;
    float dz = az - bz;
    return (dx * dx + dy * dy) + dz * dz;
}

// Packed 2-wide exact sqdist: same op order per component, no contraction.
// Targets v_pk_add_f32 / v_pk_mul_f32 (VOP3P); falls back to 2x scalar.
__device__ __forceinline__ f32x2 sqdist2_exact(f32x2 px, f32x2 py, f32x2 pz,
                                               f32x2 cx2, f32x2 cy2, f32x2 cz2) {
#pragma clang fp contract(off)
    f32x2 dx = px - cx2;
    f32x2 dy = py - cy2;
    f32x2 dz = pz - cz2;
    return (dx * dx + dy * dy) + dz * dz;
}

// u64 max (compare-select, ~3 VALU insts, branchless)
__device__ __forceinline__ unsigned long long u64max(unsigned long long a,
                                                     unsigned long long b) {
    return (a > b) ? a : b;
}

// DPP wave-64 reduce steps (gfx9 lineage: row_shr + row_bcast legal on CDNA4).
// u64 max step via DPP (2 dpp movs + u64 cmp/select, pure VALU). Identity 0
// is safe: keys are always non-negative (dist bits in the high half).
template <int CTRL>
__device__ __forceinline__ unsigned long long dpp_u64max_step(unsigned long long k) {
    int lo = __builtin_amdgcn_update_dpp(0, (int)(unsigned)(k & 0xffffffffu),
                                         CTRL, 0xf, 0xf, false);
    int hi = __builtin_amdgcn_update_dpp(0, (int)(unsigned)(k >> 32),
                                         CTRL, 0xf, 0xf, false);
    unsigned long long o = ((unsigned long long)(unsigned)hi << 32) | (unsigned)lo;
    return (o > k) ? o : k;
}
#define ROW_SHR1 0x111
#define ROW_SHR2 0x112
#define ROW_SHR4 0x114
#define ROW_SHR8 0x118
#define ROW_BC15 0x142
#define ROW_BC31 0x143

// full-wave min/max butterfly (init-time only, not on the hot path)
__device__ __forceinline__ void wave_minmax(float x, float& lo, float& hi) {
    float a = x, b = x;
#pragma unroll
    for (int off = 1; off < 64; off <<= 1) {
        a = fminf(a, __shfl_xor(a, off));
        b = fmaxf(b, __shfl_xor(b, off));
    }
    lo = a;
    hi = b;
}

// ---------------------------------------------------------------------------
// Weight transpose prep: w1T[c][64], w2T[j][64], w3T[j][128]
// ---------------------------------------------------------------------------
__global__ void prep_kernel(const float* __restrict__ w1, const float* __restrict__ w2,
                            const float* __restrict__ w3, float* __restrict__ w1T,
                            float* __restrict__ w2T, float* __restrict__ w3T) {
    for (int i = threadIdx.x; i < 192; i += 256) {
        int oc = i / 3, c = i % 3;
        w1T[c * 64 + oc] = w1[i];
    }
    for (int i = threadIdx.x; i < 4096; i += 256) {
        int oc = i >> 6, j = i & 63;
        w2T[j * 64 + oc] = w2[i];
    }
    for (int i = threadIdx.x; i < 8192; i += 256) {
        int oc = i >> 6, j = i & 63;
        w3T[j * 128 + oc] = w3[i];
    }
}

// spread 3-bit value to bit positions 0,3,6
__device__ __forceinline__ int part3(int v) {
    return (v & 1) | ((v & 2) << 2) | ((v & 4) << 4);
}

#define P4_LIST(X) X(0) X(1) X(2) X(3)

// ---------------------------------------------------------------------------
// FPS — R19 (verified best, 1552us): byte-identical this round. 1024 threads
// / 16 waves (4/SIMD); wave owns 8 bricks of 64 Morton slots, 8 pts/thread
// as 4 packed f32x2 pairs; brick bboxes lanes 0..7; prune vs wave_bv (exact
// skip); packed branchless update; joint u64 argmax (tree + 6-step DPP);
// red[2][16]; cross-wave tail 4 DPP steps; one barrier/iter parity buffer.
// ---------------------------------------------------------------------------
__global__ __attribute__((amdgpu_flat_work_group_size(1024, 1024),
                          amdgpu_waves_per_eu(4, 4)))
void fps_kernel(const float* __restrict__ xyz_all,
                float4* __restrict__ wsSorted,
                float4* __restrict__ wsCtr,
                float* __restrict__ out0) {
    const int b = blockIdx.x;
    const float* xyz = xyz_all + (size_t)b * NN * 3;
    float4* sorted = wsSorted + (size_t)b * NN;
    float4* ctr = wsCtr + (size_t)b * SS;
    float* o0 = out0 + (size_t)b * 3 * SS;

    __shared__ float xLds[NN];            // 32KB
    __shared__ float yLds[NN];            // 32KB
    __shared__ float zLds[NN];            // 32KB
    __shared__ float4 ctrLds[SS];         // 32KB
    __shared__ int cellCnt[512];
    __shared__ int cellBase[512];
    __shared__ unsigned long long red[2][16];

    const int tid = threadIdx.x;
    const int wid = tid >> 6;
    const int lane = tid & 63;

    // --- pass 1: per-Morton-cell counts (8 pts/thread) + stage xyz in LDS
    if (tid < 512) cellCnt[tid] = 0;
    __syncthreads();
    int cellReg[8];
#pragma unroll
    for (int j = 0; j < 8; ++j) {
        int p = tid + j * 1024;
        float x = xyz[p * 3 + 0], y = xyz[p * 3 + 1], z = xyz[p * 3 + 2];
        xLds[p] = x; yLds[p] = y; zLds[p] = z;
        int qx = min(7, (int)(x * 8.0f));
        int qy = min(7, (int)(y * 8.0f));
        int qz = min(7, (int)(z * 8.0f));
        cellReg[j] = part3(qx) | (part3(qy) << 1) | (part3(qz) << 2);
        atomicAdd(&cellCnt[cellReg[j]], 1);
    }
    __syncthreads();
    int myCnt = (tid < 512) ? cellCnt[tid] : 0;
    // inclusive Hillis-Steele scan over 512 cells (threads 0..511)
    for (int off = 1; off < 512; off <<= 1) {
        int v = (tid < 512 && tid >= off) ? cellCnt[tid - off] : 0;
        __syncthreads();
        if (tid < 512) cellCnt[tid] += v;
        __syncthreads();
    }
    if (tid < 512) cellBase[tid] = cellCnt[tid] - myCnt;
    __syncthreads();
    // --- pass 2: scatter to global ws in PLAIN Morton-slot order. The reader
    // (brick i, lane l <-> slot (wid*8+i)*64 + l) is coalesced directly.
#pragma unroll
    for (int j = 0; j < 8; ++j) {
        int p = tid + j * 1024;
        float x = xLds[p], y = yLds[p], z = zLds[p];
        int pos = atomicAdd(&cellBase[cellReg[j]], 1);
        sorted[pos] = make_float4(x, y, z, __int_as_float(p));
    }
    __threadfence();
    __syncthreads();

    // --- load 8 bricks as 4 packed pairs: pair j holds bricks wid*8+2j (.x)
    // and wid*8+2j+1 (.y); lane l owns slot (brick)*64 + l of each.
#define DECL_PR(j)                                                   \
    f32x2 px##j, py##j, pz##j, dist##j;                              \
    int ndA##j, ndB##j;                                              \
    {                                                                \
        float4 va = sorted[(wid * 8 + 2 * j) * 64 + lane];           \
        float4 vb = sorted[(wid * 8 + 2 * j + 1) * 64 + lane];       \
        px##j = (f32x2){va.x, vb.x};                                 \
        py##j = (f32x2){va.y, vb.y};                                 \
        pz##j = (f32x2){va.z, vb.z};                                 \
        ndA##j = ~__float_as_int(va.w);                              \
        ndB##j = ~__float_as_int(vb.w);                              \
        dist##j = (f32x2){1e10f, 1e10f};                             \
    }
    P4_LIST(DECL_PR)

    // --- brick bboxes: brick 2j from pair j component x, brick 2j+1 from y.
    // Computed via shfl butterflies (one-time); lane i (<8) keeps brick i's.
    float bbxlo = 0.f, bbxhi = 0.f, bbylo = 0.f, bbyhi = 0.f,
          bbzlo = 0.f, bbzhi = 0.f;
#define BRICK_BB2(j)                                              \
    {                                                             \
        float xl, xh, yl, yh, zl, zh;                             \
        wave_minmax(px##j.x, xl, xh);                             \
        wave_minmax(py##j.x, yl, yh);                             \
        wave_minmax(pz##j.x, zl, zh);                             \
        if (lane == 2 * j) {                                      \
            bbxlo = xl; bbxhi = xh;                               \
            bbylo = yl; bbyhi = yh;                               \
            bbzlo = zl; bbzhi = zh;                               \
        }                                                         \
        wave_minmax(px##j.y, xl, xh);                             \
        wave_minmax(py##j.y, yl, yh);                             \
        wave_minmax(pz##j.y, zl, zh);                             \
        if (lane == 2 * j + 1) {                                  \
            bbxlo = xl; bbxhi = xh;                               \
            bbylo = yl; bbyhi = yh;                               \
            bbzlo = zl; bbzhi = zh;                               \
        }                                                         \
    }
    P4_LIST(BRICK_BB2)

    float cx = xLds[0], cy = yLds[0], cz = zLds[0];
    if (tid == 0) ctrLds[0] = make_float4(cx, cy, cz, 0.0f);

    unsigned long long waveKey =
        ((unsigned long long)__float_as_uint(1e10f) << 32) | 0xFFFFFFFFull;
    float wave_bv = 1e10f;  // max min-dist over this wave's 512 points (cached)

    for (int s = 1; s < SS; ++s) {
        const int par = s & 1;
        // brick-granular prune vs wave_bv: lane i<8 tests brick i's lower
        // bound; all-clear -> whole wave provably unchanged (exact skip).
        float ddx = fmaxf(fmaxf(bbxlo - cx, cx - bbxhi), 0.0f);
        float ddy = fmaxf(fmaxf(bbylo - cy, cy - bbyhi), 0.0f);
        float ddz = fmaxf(fmaxf(bbzlo - cz, cz - bbzhi), 0.0f);
        float lb2 = (ddx * ddx + ddy * ddy) + ddz * ddz;
        bool act = (lane < 8) && (lb2 * 0.999f < wave_bv);
        if (__ballot(act)) {
            // branchless packed full update (reference semantics: min over
            // every point, every iteration — trivially exact)
            const f32x2 c2x = (f32x2){cx, cx};
            const f32x2 c2y = (f32x2){cy, cy};
            const f32x2 c2z = (f32x2){cz, cz};
#define UPD_PR(j)                                                        \
    {                                                                    \
        f32x2 d = sqdist2_exact(px##j, py##j, pz##j, c2x, c2y, c2z);     \
        dist##j.x = fminf(dist##j.x, d.x);                               \
        dist##j.y = fminf(dist##j.y, d.y);                               \
    }
            P4_LIST(UPD_PR)
            // joint u64 argmax over the 8 bricks: key = (dist<<32) | ~od
#define KEY_PR(j)                                                        \
    unsigned long long kA##j =                                           \
        ((unsigned long long)__float_as_uint(dist##j.x) << 32) |         \
        (unsigned)ndA##j;                                                \
    unsigned long long kB##j =                                           \
        ((unsigned long long)__float_as_uint(dist##j.y) << 32) |         \
        (unsigned)ndB##j;
            P4_LIST(KEY_PR)
            // 3-level ILP tree over the 8 per-lane keys
            unsigned long long t0 = u64max(kA0, kB0), t1 = u64max(kA1, kB1),
                               t2 = u64max(kA2, kB2), t3 = u64max(kA3, kB3);
            unsigned long long K = u64max(u64max(t0, t1), u64max(t2, t3));
            // cross-lane: ONE 6-step DPP u64max chain -> lane 63 writes red
            K = dpp_u64max_step<ROW_SHR1>(K);
            K = dpp_u64max_step<ROW_SHR2>(K);
            K = dpp_u64max_step<ROW_SHR4>(K);
            K = dpp_u64max_step<ROW_SHR8>(K);
            K = dpp_u64max_step<ROW_BC15>(K);
            K = dpp_u64max_step<ROW_BC31>(K);
            if (lane == 63) red[par][wid] = K;
            // refresh cached wave key + wave_bv (for future quiet iters)
            unsigned wlo = (unsigned)__builtin_amdgcn_readlane(
                (int)(unsigned)(K & 0xffffffffu), 63);
            unsigned whi = (unsigned)__builtin_amdgcn_readlane(
                (int)(unsigned)(K >> 32), 63);
            waveKey = ((unsigned long long)whi << 32) | wlo;
            wave_bv = __int_as_float((int)whi);
        } else {
            if (lane == 0) red[par][wid] = waveKey;
        }
        __syncthreads();  // lgkm-only drain (no global ops in loop)
        // cross-wave reduce: ONE lane-indexed b64 read + 4 DPP row_shr u64-max
        // steps (lane 15 = max over slots 0..15); the winning index is the
        // low half of the max key -> one readlane, no ballot.
        unsigned long long k = red[par][lane & 15];
        k = dpp_u64max_step<ROW_SHR1>(k);
        k = dpp_u64max_step<ROW_SHR2>(k);
        k = dpp_u64max_step<ROW_SHR4>(k);
        k = dpp_u64max_step<ROW_SHR8>(k);
        unsigned blo = (unsigned)__builtin_amdgcn_readlane(
            (int)(unsigned)(k & 0xffffffffu), 15);
        int wiu = (int)(~blo);  // uniform (SGPR) winner index
        cx = xLds[wiu];  // 3 independent broadcast ds_read_b32
        cy = yLds[wiu];
        cz = zLds[wiu];
        if (tid == 0) ctrLds[s] = make_float4(cx, cy, cz, 0.0f);
    }

    // --- single coalesced write-out of all centers
    __syncthreads();
    for (int s = tid; s < SS; s += 1024) {
        float4 c = ctrLds[s];
        o0[s] = c.x;
        o0[SS + s] = c.y;
        o0[2 * SS + s] = c.z;
        ctr[s] = c;
    }
}

// ---------------------------------------------------------------------------
// Fused ball-query + MLP + maxpool. Block = 128 threads (2 waves), 2 centers.
// R20: weight loads vectorized to float4 (w2T/w3T rows are 16B-aligned:
// w2T+j*64+cb*32 and w3T+j*128+cb*64 are 128B-aligned). Cuts per-thread
// weight-load instructions 4x (6144 -> 1536) — the kernel was VMEM+VALU
// issue-bound with loads ~ FMA count (each wrow[i] a distinct scalar dword).
// Math order per channel unchanged (acc[i] chain identical) -> bit-exact.
// ---------------------------------------------------------------------------
__global__ __launch_bounds__(128) void bqmlp_kernel(const float* __restrict__ xyz_all,
                                                    const float4* __restrict__ wsCtr,
                                                    const float* __restrict__ w1T,
                                                    const float* __restrict__ b1,
                                                    const float* __restrict__ w2T,
                                                    const float* __restrict__ b2,
                                                    const float* __restrict__ w3T,
                                                    const float* __restrict__ b3,
                                                    float* __restrict__ out1) {
    const int b = blockIdx.x >> 10;            // 1024 blocks per batch
    const int s0 = (blockIdx.x & 1023) * 2;    // 2 centers per block
    const float* xyz = xyz_all + (size_t)b * NN * 3;

    __shared__ float relF[2 * KNB * 3];  // [64 rows][3]
    __shared__ float hT[64 * 64];        // [ch][row] — holds h1, then h2

    const int tid = threadIdx.x;
    const int cb = __builtin_amdgcn_readfirstlane(tid >> 6);  // wave id (uniform)
    const int l = tid & 63;

    // ---- ball query: wave cb handles center s0+cb
    {
        float4 cc = wsCtr[(size_t)b * SS + s0 + cb];
        float ccx = cc.x, ccy = cc.y, ccz = cc.z;
        const float R2 = (float)(0.2 * 0.2);
        int total = 0;
        float fx = 0.f, fy = 0.f, fz = 0.f;
        bool have = false;
        for (int chunk = 0; chunk < 128 && total < KNB; ++chunk) {
            int p = chunk * 64 + l;
            float x = xyz[p * 3 + 0], y = xyz[p * 3 + 1], z = xyz[p * 3 + 2];
            float d = sqdist_exact(ccx, ccy, ccz, x, y, z);
            bool hit = (d <= R2);
            unsigned long long mask = __ballot(hit);
            int cnt = __popcll(mask);
            if (cnt) {
                int pos = total + __popcll(mask & ((1ull << l) - 1ull));
                float rx = x - ccx, ry = y - ccy, rz = z - ccz;  // single subs: exact
                if (hit && pos < KNB) {
                    relF[(cb * KNB + pos) * 3 + 0] = rx;
                    relF[(cb * KNB + pos) * 3 + 1] = ry;
                    relF[(cb * KNB + pos) * 3 + 2] = rz;
                }
                if (hit && pos == 0) { fx = rx; fy = ry; fz = rz; have = true; }
                total += cnt;
            }
        }
        unsigned long long hm = __ballot(have);
        if (total < KNB) {
            int src = __ffsll((long long)hm) - 1;
            float gx = __shfl(fx, src), gy = __shfl(fy, src), gz = __shfl(fz, src);
            if (l >= total && l < KNB) {
                relF[(cb * KNB + l) * 3 + 0] = gx;
                relF[(cb * KNB + l) * 3 + 1] = gy;
                relF[(cb * KNB + l) * 3 + 2] = gz;
            }
        }
    }
    __syncthreads();

    const int r = l;  // row 0..63: rows 0..31 center s0, rows 32..63 center s0+1

    // ---- layer 1: rel(3) -> 64, thread covers ch block cb*32..+31 for row r
    {
        float rx = relF[r * 3 + 0], ry = relF[r * 3 + 1], rz = relF[r * 3 + 2];
#pragma unroll
        for (int i = 0; i < 32; ++i) {
            int ch = cb * 32 + i;
            float h = b1[ch];
            h = fmaf(rx, w1T[0 * 64 + ch], h);
            h = fmaf(ry, w1T[1 * 64 + ch], h);
            h = fmaf(rz, w1T[2 * 64 + ch], h);
            hT[ch * 64 + r] = fmaxf(h, 0.0f);
        }
    }
    __syncthreads();

    // ---- layer 2: 64 -> 64 (reads h1 from hT; after barrier, h2 overwrites)
    {
        float acc[32];
#pragma unroll
        for (int i = 0; i < 32; ++i) acc[i] = b2[cb * 32 + i];
#pragma unroll 4
        for (int j = 0; j < 64; ++j) {
            float a = hT[j * 64 + r];
            const float4* wrow = (const float4*)(w2T + j * 64 + cb * 32);
#pragma unroll
            for (int i4 = 0; i4 < 8; ++i4) {
                float4 w = wrow[i4];
                acc[i4 * 4 + 0] = fmaf(a, w.x, acc[i4 * 4 + 0]);
                acc[i4 * 4 + 1] = fmaf(a, w.y, acc[i4 * 4 + 1]);
                acc[i4 * 4 + 2] = fmaf(a, w.z, acc[i4 * 4 + 2]);
                acc[i4 * 4 + 3] = fmaf(a, w.w, acc[i4 * 4 + 3]);
            }
        }
        __syncthreads();  // all h1 reads complete before overwrite
#pragma unroll
        for (int i = 0; i < 32; ++i) hT[(cb * 32 + i) * 64 + r] = fmaxf(acc[i], 0.0f);
    }
    __syncthreads();

    // ---- layer 3: 64 -> 128, fused relu + maxpool over the 32 rows/center
    {
        float acc[64];
#pragma unroll
        for (int i = 0; i < 64; ++i) acc[i] = b3[cb * 64 + i];
#pragma unroll 2
        for (int j = 0; j < 64; ++j) {
            float a = hT[j * 64 + r];
            const float4* wrow = (const float4*)(w3T + j * 128 + cb * 64);
#pragma unroll
            for (int i4 = 0; i4 < 16; ++i4) {
                float4 w = wrow[i4];
                acc[i4 * 4 + 0] = fmaf(a, w.x, acc[i4 * 4 + 0]);
                acc[i4 * 4 + 1] = fmaf(a, w.y, acc[i4 * 4 + 1]);
                acc[i4 * 4 + 2] = fmaf(a, w.z, acc[i4 * 4 + 2]);
                acc[i4 * 4 + 3] = fmaf(a, w.w, acc[i4 * 4 + 3]);
            }
        }
#pragma unroll
        for (int i = 0; i < 64; ++i) {
            float v = fmaxf(acc[i], 0.0f);
            v = fmaxf(v, __shfl_xor(v, 1));
            v = fmaxf(v, __shfl_xor(v, 2));
            v = fmaxf(v, __shfl_xor(v, 4));
            v = fmaxf(v, __shfl_xor(v, 8));
            v = fmaxf(v, __shfl_xor(v, 16));
            acc[i] = v;
        }
        if ((l & 31) == 0) {
            int sA = s0 + (l >> 5);
            float* op = out1 + ((size_t)b * 128 + cb * 64) * SS + sA;
#pragma unroll
            for (int i = 0; i < 64; ++i) op[(size_t)i * SS] = acc[i];
        }
    }
}

extern "C" void kernel_launch(void* const* d_in, const int* in_sizes, int n_in,
                              void* d_out, int out_size, void* d_ws, size_t ws_size,
                              hipStream_t stream) {
    (void)in_sizes; (void)n_in; (void)out_size; (void)ws_size;
    const float* xyz = (const float*)d_in[0];
    // d_in[1] = features : unused by the reference
    const float* w1 = (const float*)d_in[2];
    const float* b1 = (const float*)d_in[3];
    const float* w2 = (const float*)d_in[4];
    const float* b2 = (const float*)d_in[5];
    const float* w3 = (const float*)d_in[6];
    const float* b3 = (const float*)d_in[7];
    float* out = (float*)d_out;

    // workspace layout
    float4* wsCtr = (float4*)d_ws;              // B*S float4      (256 KB)
    float4* wsSorted = wsCtr + BB * SS;         // B*N float4      (1 MB)
    float* w1T = (float*)(wsSorted + BB * NN);  // 192 f
    float* w2T = w1T + 192;                     // 4096 f
    float* w3T = w2T + 4096;                    // 8192 f

    prep_kernel<<<1, 256, 0, stream>>>(w1, w2, w3, w1T, w2T, w3T);
    fps_kernel<<<BB, 1024, 0, stream>>>(xyz, wsSorted, wsCtr, out);
    bqmlp_kernel<<<BB * (SS / 2), 128, 0, stream>>>(xyz, wsCtr, w1T, b1, w2T, b2,
                                                    w3T, b3, out + BB * 3 * SS);
}

// Round 11
// 1751.879 us; speedup vs baseline: 1.4609x; 1.0744x over previous
//
#include <hip/hip_runtime.h>
#include <cstdint>
#include <cstddef>

#define BB 8
#define NN 8192
#define SS 2048
#define KNB 32
#define NTASKS (BB * (SS / 16))

typedef float f32x2 __attribute__((ext_vector_type(2)));

// Bit-exact squared distance matching numpy: (a-b) per component, squares,
// left-to-right sum, no FMA contraction.
__device__ __forceinline__ float sqdist_exact(float ax, float ay, float az,
                                              float bx, float by, float bz) {
#pragma clang fp contract(off)
    float dx = ax - bx;
    float dy = ay - by;
    float dz = az - bz;
    return (dx * dx + dy * dy) + dz * dz;
}

// Packed 2-wide exact sqdist: same op order per component, no contraction.
__device__ __forceinline__ f32x2 sqdist2_exact(f32x2 px, f32x2 py, f32x2 pz,
                                               f32x2 cx2, f32x2 cy2, f32x2 cz2) {
#pragma clang fp contract(off)
    f32x2 dx = px - cx2;
    f32x2 dy = py - cy2;
    f32x2 dz = pz - cz2;
    return (dx * dx + dy * dy) + dz * dz;
}

// u64 max (compare-select, branchless)
__device__ __forceinline__ unsigned long long u64max(unsigned long long a,
                                                     unsigned long long b) {
    return (a > b) ? a : b;
}

// DPP u64 max step (row_shr/row_bcast legal on CDNA4). Identity 0 safe.
template <int CTRL>
__device__ __forceinline__ unsigned long long dpp_u64max_step(unsigned long long k) {
    int lo = __builtin_amdgcn_update_dpp(0, (int)(unsigned)(k & 0xffffffffu),
                                         CTRL, 0xf, 0xf, false);
    int hi = __builtin_amdgcn_update_dpp(0, (int)(unsigned)(k >> 32),
                                         CTRL, 0xf, 0xf, false);
    unsigned long long o = ((unsigned long long)(unsigned)hi << 32) | (unsigned)lo;
    return (o > k) ? o : k;
}
#define ROW_SHR1 0x111
#define ROW_SHR2 0x112
#define ROW_SHR4 0x114
#define ROW_SHR8 0x118
#define ROW_BC15 0x142
#define ROW_BC31 0x143

// full-wave min/max butterfly (init-time only)
__device__ __forceinline__ void wave_minmax(float x, float& lo, float& hi) {
    float a = x, b = x;
#pragma unroll
    for (int off = 1; off < 64; off <<= 1) {
        a = fminf(a, __shfl_xor(a, off));
        b = fmaxf(b, __shfl_xor(b, off));
    }
    lo = a;
    hi = b;
}

// ---------------------------------------------------------------------------
// Weight transpose prep + zero the producer/consumer sync counters (runs at
// the head of every launch/replay, so re-runs are self-initializing).
// ---------------------------------------------------------------------------
__global__ void prep_kernel(const float* __restrict__ w1, const float* __restrict__ w2,
                            const float* __restrict__ w3, float* __restrict__ w1T,
                            float* __restrict__ w2T, float* __restrict__ w3T,
                            int* __restrict__ syncWs) {
    if (threadIdx.x < 12) syncWs[threadIdx.x] = 0;
    for (int i = threadIdx.x; i < 192; i += 256) {
        int oc = i / 3, c = i % 3;
        w1T[c * 64 + oc] = w1[i];
    }
    for (int i = threadIdx.x; i < 4096; i += 256) {
        int oc = i >> 6, j = i & 63;
        w2T[j * 64 + oc] = w2[i];
    }
    for (int i = threadIdx.x; i < 8192; i += 256) {
        int oc = i >> 6, j = i & 63;
        w3T[j * 128 + oc] = w3[i];
    }
}

// spread 3-bit value to bit positions 0,3,6
__device__ __forceinline__ int part3(int v) {
    return (v & 1) | ((v & 2) << 2) | ((v & 4) << 4);
}

#define P4_LIST(X) X(0) X(1) X(2) X(3)

// ---------------------------------------------------------------------------
// Consumer loop: 16-center tasks from a global queue. Block = 1024 threads =
// 8 sub-blocks of 128 (2 waves / 2 centers each) — the verified bqmlp body.
// Layer3 split into two 32-channel halves (VGPR <=128 for the 1024-thr
// block); per-channel math order identical -> bit-exact. Producers call this
// after finishing FPS, so completion never depends on scheduling.
// ---------------------------------------------------------------------------
__device__ __forceinline__ void consume_tasks(
    char* smemRaw, int* taskS, const float* __restrict__ xyz_all,
    const float4* __restrict__ wsCtr, const float* __restrict__ w1T,
    const float* __restrict__ b1, const float* __restrict__ w2T,
    const float* __restrict__ b2, const float* __restrict__ w3T,
    const float* __restrict__ b3, float* __restrict__ out1,
    int* __restrict__ prog, int* __restrict__ taskCtr) {
    const int tid = threadIdx.x;
    const int l = tid & 63;
    const int sub = tid >> 7;                                   // 0..7
    const int cb = __builtin_amdgcn_readfirstlane((tid >> 6) & 1);
    float* hT = ((float*)smemRaw) + sub * 4096;                 // [64 ch][64 rows]
    float* relF = ((float*)smemRaw) + 8 * 4096 + sub * 192;     // [64 rows][3]

    for (;;) {
        if (tid == 0) *taskS = atomicAdd(taskCtr, 1);
        __syncthreads();
        const int t = *taskS;
        if (t >= NTASKS) break;
        const int bb = t >> 7;
        const int base = (t & 127) << 4;
        if (tid == 0) {
            while (atomicAdd(&prog[bb], 0) < base + 16) __builtin_amdgcn_s_sleep(16);
        }
        __syncthreads();
        __threadfence();  // acquire: invalidate stale lines before reading ctr
        const int s0 = base + sub * 2;
        const float* xyz = xyz_all + (size_t)bb * NN * 3;

        // ---- ball query: wave cb of this sub handles center s0+cb
        {
            float4 cc = wsCtr[(size_t)bb * SS + s0 + cb];
            float ccx = cc.x, ccy = cc.y, ccz = cc.z;
            const float R2 = (float)(0.2 * 0.2);
            int total = 0;
            float fx = 0.f, fy = 0.f, fz = 0.f;
            bool have = false;
            for (int chunk = 0; chunk < 128 && total < KNB; ++chunk) {
                int p = chunk * 64 + l;
                float x = xyz[p * 3 + 0], y = xyz[p * 3 + 1], z = xyz[p * 3 + 2];
                float d = sqdist_exact(ccx, ccy, ccz, x, y, z);
                bool hit = (d <= R2);
                unsigned long long mask = __ballot(hit);
                int cnt = __popcll(mask);
                if (cnt) {
                    int pos = total + __popcll(mask & ((1ull << l) - 1ull));
                    float rx = x - ccx, ry = y - ccy, rz = z - ccz;
                    if (hit && pos < KNB) {
                        relF[(cb * KNB + pos) * 3 + 0] = rx;
                        relF[(cb * KNB + pos) * 3 + 1] = ry;
                        relF[(cb * KNB + pos) * 3 + 2] = rz;
                    }
                    if (hit && pos == 0) { fx = rx; fy = ry; fz = rz; have = true; }
                    total += cnt;
                }
            }
            unsigned long long hm = __ballot(have);
            if (total < KNB) {
                int src = __ffsll((long long)hm) - 1;
                float gx = __shfl(fx, src), gy = __shfl(fy, src), gz = __shfl(fz, src);
                if (l >= total && l < KNB) {
                    relF[(cb * KNB + l) * 3 + 0] = gx;
                    relF[(cb * KNB + l) * 3 + 1] = gy;
                    relF[(cb * KNB + l) * 3 + 2] = gz;
                }
            }
        }
        __syncthreads();

        const int r = l;  // rows 0..31 center s0, rows 32..63 center s0+1

        // ---- layer 1: rel(3) -> 64
        {
            float rx = relF[r * 3 + 0], ry = relF[r * 3 + 1], rz = relF[r * 3 + 2];
#pragma unroll
            for (int i = 0; i < 32; ++i) {
                int ch = cb * 32 + i;
                float h = b1[ch];
                h = fmaf(rx, w1T[0 * 64 + ch], h);
                h = fmaf(ry, w1T[1 * 64 + ch], h);
                h = fmaf(rz, w1T[2 * 64 + ch], h);
                hT[ch * 64 + r] = fmaxf(h, 0.0f);
            }
        }
        __syncthreads();

        // ---- layer 2: 64 -> 64 (h2 overwrites h1 in place after barrier)
        {
            float acc[32];
#pragma unroll
            for (int i = 0; i < 32; ++i) acc[i] = b2[cb * 32 + i];
#pragma unroll 2
            for (int j = 0; j < 64; ++j) {
                float a = hT[j * 64 + r];
                const float4* wrow = (const float4*)(w2T + j * 64 + cb * 32);
#pragma unroll
                for (int i4 = 0; i4 < 8; ++i4) {
                    float4 w = wrow[i4];
                    acc[i4 * 4 + 0] = fmaf(a, w.x, acc[i4 * 4 + 0]);
                    acc[i4 * 4 + 1] = fmaf(a, w.y, acc[i4 * 4 + 1]);
                    acc[i4 * 4 + 2] = fmaf(a, w.z, acc[i4 * 4 + 2]);
                    acc[i4 * 4 + 3] = fmaf(a, w.w, acc[i4 * 4 + 3]);
                }
            }
            __syncthreads();
#pragma unroll
            for (int i = 0; i < 32; ++i) hT[(cb * 32 + i) * 64 + r] = fmaxf(acc[i], 0.0f);
        }
        __syncthreads();

        // ---- layer 3: 64 -> 128 in two 32-channel halves + maxpool + store
#pragma unroll 1
        for (int half = 0; half < 2; ++half) {
            float acc[32];
#pragma unroll
            for (int i = 0; i < 32; ++i) acc[i] = b3[cb * 64 + half * 32 + i];
#pragma unroll 2
            for (int j = 0; j < 64; ++j) {
                float a = hT[j * 64 + r];
                const float4* wrow = (const float4*)(w3T + j * 128 + cb * 64 + half * 32);
#pragma unroll
                for (int i4 = 0; i4 < 8; ++i4) {
                    float4 w = wrow[i4];
                    acc[i4 * 4 + 0] = fmaf(a, w.x, acc[i4 * 4 + 0]);
                    acc[i4 * 4 + 1] = fmaf(a, w.y, acc[i4 * 4 + 1]);
                    acc[i4 * 4 + 2] = fmaf(a, w.z, acc[i4 * 4 + 2]);
                    acc[i4 * 4 + 3] = fmaf(a, w.w, acc[i4 * 4 + 3]);
                }
            }
#pragma unroll
            for (int i = 0; i < 32; ++i) {
                float v = fmaxf(acc[i], 0.0f);
                v = fmaxf(v, __shfl_xor(v, 1));
                v = fmaxf(v, __shfl_xor(v, 2));
                v = fmaxf(v, __shfl_xor(v, 4));
                v = fmaxf(v, __shfl_xor(v, 8));
                v = fmaxf(v, __shfl_xor(v, 16));
                acc[i] = v;
            }
            if ((l & 31) == 0) {
                int sA = s0 + (l >> 5);
                float* op = out1 + ((size_t)bb * 128 + cb * 64 + half * 32) * SS + sA;
#pragma unroll
                for (int i = 0; i < 32; ++i) op[(size_t)i * SS] = acc[i];
            }
        }
        __syncthreads();  // protect relF/hT before next task
    }
}

// ---------------------------------------------------------------------------
// Fused producer-consumer kernel. 256 blocks x 1024 threads, ~134KB LDS ->
// 1 block/CU. Blocks 0..7: R19 FPS (verified, 1552us) + per-iter global
// center store + chunked publish (threadfence + atomicExch every 16 iters).
// Blocks 8..255: consume bqmlp tasks as centers become available. Producers
// fall into the consumer loop when done -> correctness independent of
// scheduling (worst case degenerates to serial = current behavior).
// ---------------------------------------------------------------------------
__global__ __attribute__((amdgpu_flat_work_group_size(1024, 1024)))
void fused_kernel(const float* __restrict__ xyz_all,
                  float4* __restrict__ wsSorted,
                  float4* __restrict__ wsCtr,
                  float* __restrict__ out0,
                  const float* __restrict__ w1T, const float* __restrict__ b1,
                  const float* __restrict__ w2T, const float* __restrict__ b2,
                  const float* __restrict__ w3T, const float* __restrict__ b3,
                  float* __restrict__ out1, int* __restrict__ syncWs) {
    __shared__ __align__(16) char smemRaw[137216];
    __shared__ int taskS;
    int* prog = syncWs;        // [8] published-center counts
    int* taskCtr = syncWs + 8;

    const int tid = threadIdx.x;
    const int wid = tid >> 6;
    const int lane = tid & 63;

    if (blockIdx.x < BB) {
        // ================= producer: FPS for batch b =================
        const int b = blockIdx.x;
        const float* xyz = xyz_all + (size_t)b * NN * 3;
        float4* sorted = wsSorted + (size_t)b * NN;
        float4* ctr = wsCtr + (size_t)b * SS;
        float* o0 = out0 + (size_t)b * 3 * SS;

        float* xLds = (float*)smemRaw;                 // NN
        float* yLds = xLds + NN;
        float* zLds = yLds + NN;
        float4* ctrLds = (float4*)(zLds + NN);         // SS
        int* cellCnt = (int*)(ctrLds + SS);            // 512
        int* cellBase = cellCnt + 512;                 // 512
        unsigned long long* redp = (unsigned long long*)(cellBase + 512);  // [2*16]

        // --- pass 1: Morton-cell counts (8 pts/thread) + stage xyz in LDS
        if (tid < 512) cellCnt[tid] = 0;
        __syncthreads();
        int cellReg[8];
#pragma unroll
        for (int j = 0; j < 8; ++j) {
            int p = tid + j * 1024;
            float x = xyz[p * 3 + 0], y = xyz[p * 3 + 1], z = xyz[p * 3 + 2];
            xLds[p] = x; yLds[p] = y; zLds[p] = z;
            int qx = min(7, (int)(x * 8.0f));
            int qy = min(7, (int)(y * 8.0f));
            int qz = min(7, (int)(z * 8.0f));
            cellReg[j] = part3(qx) | (part3(qy) << 1) | (part3(qz) << 2);
            atomicAdd(&cellCnt[cellReg[j]], 1);
        }
        __syncthreads();
        int myCnt = (tid < 512) ? cellCnt[tid] : 0;
        for (int off = 1; off < 512; off <<= 1) {
            int v = (tid < 512 && tid >= off) ? cellCnt[tid - off] : 0;
            __syncthreads();
            if (tid < 512) cellCnt[tid] += v;
            __syncthreads();
        }
        if (tid < 512) cellBase[tid] = cellCnt[tid] - myCnt;
        __syncthreads();
        // --- pass 2: scatter to global ws in Morton order
#pragma unroll
        for (int j = 0; j < 8; ++j) {
            int p = tid + j * 1024;
            float x = xLds[p], y = yLds[p], z = zLds[p];
            int pos = atomicAdd(&cellBase[cellReg[j]], 1);
            sorted[pos] = make_float4(x, y, z, __int_as_float(p));
        }
        __threadfence();
        __syncthreads();

        // --- 8 bricks as 4 packed pairs
#define DECL_PR(j)                                                   \
        f32x2 px##j, py##j, pz##j, dist##j;                          \
        int ndA##j, ndB##j;                                          \
        {                                                            \
            float4 va = sorted[(wid * 8 + 2 * j) * 64 + lane];       \
            float4 vb = sorted[(wid * 8 + 2 * j + 1) * 64 + lane];   \
            px##j = (f32x2){va.x, vb.x};                             \
            py##j = (f32x2){va.y, vb.y};                             \
            pz##j = (f32x2){va.z, vb.z};                             \
            ndA##j = ~__float_as_int(va.w);                          \
            ndB##j = ~__float_as_int(vb.w);                          \
            dist##j = (f32x2){1e10f, 1e10f};                         \
        }
        P4_LIST(DECL_PR)

        float bbxlo = 0.f, bbxhi = 0.f, bbylo = 0.f, bbyhi = 0.f,
              bbzlo = 0.f, bbzhi = 0.f;
#define BRICK_BB2(j)                                              \
        {                                                         \
            float xl, xh, yl, yh, zl, zh;                         \
            wave_minmax(px##j.x, xl, xh);                         \
            wave_minmax(py##j.x, yl, yh);                         \
            wave_minmax(pz##j.x, zl, zh);                         \
            if (lane == 2 * j) {                                  \
                bbxlo = xl; bbxhi = xh;                           \
                bbylo = yl; bbyhi = yh;                           \
                bbzlo = zl; bbzhi = zh;                           \
            }                                                     \
            wave_minmax(px##j.y, xl, xh);                         \
            wave_minmax(py##j.y, yl, yh);                         \
            wave_minmax(pz##j.y, zl, zh);                         \
            if (lane == 2 * j + 1) {                              \
                bbxlo = xl; bbxhi = xh;                           \
                bbylo = yl; bbyhi = yh;                           \
                bbzlo = zl; bbzhi = zh;                           \
            }                                                     \
        }
        P4_LIST(BRICK_BB2)

        float cx = xLds[0], cy = yLds[0], cz = zLds[0];
        if (tid == 0) {
            float4 c4 = make_float4(cx, cy, cz, 0.0f);
            ctrLds[0] = c4;
            ctr[0] = c4;
        }

        unsigned long long waveKey =
            ((unsigned long long)__float_as_uint(1e10f) << 32) | 0xFFFFFFFFull;
        float wave_bv = 1e10f;

        for (int s = 1; s < SS; ++s) {
            const int par = s & 1;
            float ddx = fmaxf(fmaxf(bbxlo - cx, cx - bbxhi), 0.0f);
            float ddy = fmaxf(fmaxf(bbylo - cy, cy - bbyhi), 0.0f);
            float ddz = fmaxf(fmaxf(bbzlo - cz, cz - bbzhi), 0.0f);
            float lb2 = (ddx * ddx + ddy * ddy) + ddz * ddz;
            bool act = (lane < 8) && (lb2 * 0.999f < wave_bv);
            if (__ballot(act)) {
                const f32x2 c2x = (f32x2){cx, cx};
                const f32x2 c2y = (f32x2){cy, cy};
                const f32x2 c2z = (f32x2){cz, cz};
#define UPD_PR(j)                                                        \
                {                                                        \
                    f32x2 d = sqdist2_exact(px##j, py##j, pz##j, c2x, c2y, c2z); \
                    dist##j.x = fminf(dist##j.x, d.x);                   \
                    dist##j.y = fminf(dist##j.y, d.y);                   \
                }
                P4_LIST(UPD_PR)
#define KEY_PR(j)                                                        \
                unsigned long long kA##j =                               \
                    ((unsigned long long)__float_as_uint(dist##j.x) << 32) | \
                    (unsigned)ndA##j;                                    \
                unsigned long long kB##j =                               \
                    ((unsigned long long)__float_as_uint(dist##j.y) << 32) | \
                    (unsigned)ndB##j;
                P4_LIST(KEY_PR)
                unsigned long long t0 = u64max(kA0, kB0), t1 = u64max(kA1, kB1),
                                   t2 = u64max(kA2, kB2), t3 = u64max(kA3, kB3);
                unsigned long long K = u64max(u64max(t0, t1), u64max(t2, t3));
                K = dpp_u64max_step<ROW_SHR1>(K);
                K = dpp_u64max_step<ROW_SHR2>(K);
                K = dpp_u64max_step<ROW_SHR4>(K);
                K = dpp_u64max_step<ROW_SHR8>(K);
                K = dpp_u64max_step<ROW_BC15>(K);
                K = dpp_u64max_step<ROW_BC31>(K);
                if (lane == 63) redp[par * 16 + wid] = K;
                unsigned wlo = (unsigned)__builtin_amdgcn_readlane(
                    (int)(unsigned)(K & 0xffffffffu), 63);
                unsigned whi = (unsigned)__builtin_amdgcn_readlane(
                    (int)(unsigned)(K >> 32), 63);
                waveKey = ((unsigned long long)whi << 32) | wlo;
                wave_bv = __int_as_float((int)whi);
            } else {
                if (lane == 0) redp[par * 16 + wid] = waveKey;
            }
            __syncthreads();
            unsigned long long k = redp[par * 16 + (lane & 15)];
            k = dpp_u64max_step<ROW_SHR1>(k);
            k = dpp_u64max_step<ROW_SHR2>(k);
            k = dpp_u64max_step<ROW_SHR4>(k);
            k = dpp_u64max_step<ROW_SHR8>(k);
            unsigned blo = (unsigned)__builtin_amdgcn_readlane(
                (int)(unsigned)(k & 0xffffffffu), 15);
            int wiu = (int)(~blo);
            cx = xLds[wiu];
            cy = yLds[wiu];
            cz = zLds[wiu];
            if (tid == 0) {
                float4 c4 = make_float4(cx, cy, cz, 0.0f);
                ctrLds[s] = c4;
                ctr[s] = c4;  // publish progressively for consumers
            }
            if ((s & 15) == 15 && wid == 0) {
                __threadfence();  // release: centers [0, s] globally visible
                if (lane == 0) atomicExch(&prog[b], s + 1);
            }
        }

        // --- write new_xyz output (centers already in wsCtr)
        __syncthreads();
        for (int s = tid; s < SS; s += 1024) {
            float4 c = ctrLds[s];
            o0[s] = c.x;
            o0[SS + s] = c.y;
            o0[2 * SS + s] = c.z;
        }
        // help drain remaining consumer tasks (also guarantees completion
        // regardless of block scheduling)
        consume_tasks(smemRaw, &taskS, xyz_all, wsCtr, w1T, b1, w2T, b2,
                      w3T, b3, out1, prog, taskCtr);
    } else {
        // ================= consumer =================
        consume_tasks(smemRaw, &taskS, xyz_all, wsCtr, w1T, b1, w2T, b2,
                      w3T, b3, out1, prog, taskCtr);
    }
}

extern "C" void kernel_launch(void* const* d_in, const int* in_sizes, int n_in,
                              void* d_out, int out_size, void* d_ws, size_t ws_size,
                              hipStream_t stream) {
    (void)in_sizes; (void)n_in; (void)out_size; (void)ws_size;
    const float* xyz = (const float*)d_in[0];
    // d_in[1] = features : unused by the reference
    const float* w1 = (const float*)d_in[2];
    const float* b1 = (const float*)d_in[3];
    const float* w2 = (const float*)d_in[4];
    const float* b2 = (const float*)d_in[5];
    const float* w3 = (const float*)d_in[6];
    const float* b3 = (const float*)d_in[7];
    float* out = (float*)d_out;

    // workspace layout
    float4* wsCtr = (float4*)d_ws;              // B*S float4      (256 KB)
    float4* wsSorted = wsCtr + BB * SS;         // B*N float4      (1 MB)
    float* w1T = (float*)(wsSorted + BB * NN);  // 192 f
    float* w2T = w1T + 192;                     // 4096 f
    float* w3T = w2T + 4096;                    // 8192 f
    int* syncWs = (int*)(w3T + 8192);           // 12 ints (prog[8] + taskCtr)

    prep_kernel<<<1, 256, 0, stream>>>(w1, w2, w3, w1T, w2T, w3T, syncWs);
    fused_kernel<<<256, 1024, 0, stream>>>(xyz, wsSorted, wsCtr, out,
                                           w1T, b1, w2T, b2, w3T, b3,
                                           out + BB * 3 * SS, syncWs);
}

// Round 13
// 1729.751 us; speedup vs baseline: 1.4796x; 1.0128x over previous
//
#include <hip/hip_runtime.h>
#include <cstdint>
#include <cstddef>

#define BB 8
#define NN 8192
#define SS 2048
#define KNB 32
#define NTASKS (BB * (SS / 16))

typedef float f32x2 __attribute__((ext_vector_type(2)));

// Bit-exact squared distance matching numpy: (a-b) per component, squares,
// left-to-right sum, no FMA contraction.
__device__ __forceinline__ float sqdist_exact(float ax, float ay, float az,
                                              float bx, float by, float bz) {
#pragma clang fp contract(off)
    float dx = ax - bx;
    float dy = ay - by;
    float dz = az - bz;
    return (dx * dx + dy * dy) + dz * dz;
}

// Packed 2-wide exact sqdist: same op order per component, no contraction.
__device__ __forceinline__ f32x2 sqdist2_exact(f32x2 px, f32x2 py, f32x2 pz,
                                               f32x2 cx2, f32x2 cy2, f32x2 cz2) {
#pragma clang fp contract(off)
    f32x2 dx = px - cx2;
    f32x2 dy = py - cy2;
    f32x2 dz = pz - cz2;
    return (dx * dx + dy * dy) + dz * dz;
}

// u64 max (compare-select, branchless)
__device__ __forceinline__ unsigned long long u64max(unsigned long long a,
                                                     unsigned long long b) {
    return (a > b) ? a : b;
}

// DPP u64 max step (row_shr/row_bcast legal on CDNA4). Identity 0 safe.
template <int CTRL>
__device__ __forceinline__ unsigned long long dpp_u64max_step(unsigned long long k) {
    int lo = __builtin_amdgcn_update_dpp(0, (int)(unsigned)(k & 0xffffffffu),
                                         CTRL, 0xf, 0xf, false);
    int hi = __builtin_amdgcn_update_dpp(0, (int)(unsigned)(k >> 32),
                                         CTRL, 0xf, 0xf, false);
    unsigned long long o = ((unsigned long long)(unsigned)hi << 32) | (unsigned)lo;
    return (o > k) ? o : k;
}
#define ROW_SHR1 0x111
#define ROW_SHR2 0x112
#define ROW_SHR4 0x114
#define ROW_SHR8 0x118
#define ROW_BC15 0x142
#define ROW_BC31 0x143

// full-wave min/max butterfly (init-time only)
__device__ __forceinline__ void wave_minmax(float x, float& lo, float& hi) {
    float a = x, b = x;
#pragma unroll
    for (int off = 1; off < 64; off <<= 1) {
        a = fminf(a, __shfl_xor(a, off));
        b = fmaxf(b, __shfl_xor(b, off));
    }
    lo = a;
    hi = b;
}

// ---------------------------------------------------------------------------
// Weight transpose prep + zero the producer/consumer sync counters (runs at
// the head of every launch/replay, so re-runs are self-initializing).
// ---------------------------------------------------------------------------
__global__ void prep_kernel(const float* __restrict__ w1, const float* __restrict__ w2,
                            const float* __restrict__ w3, float* __restrict__ w1T,
                            float* __restrict__ w2T, float* __restrict__ w3T,
                            int* __restrict__ syncWs) {
    if (threadIdx.x < 12) syncWs[threadIdx.x] = 0;
    for (int i = threadIdx.x; i < 192; i += 256) {
        int oc = i / 3, c = i % 3;
        w1T[c * 64 + oc] = w1[i];
    }
    for (int i = threadIdx.x; i < 4096; i += 256) {
        int oc = i >> 6, j = i & 63;
        w2T[j * 64 + oc] = w2[i];
    }
    for (int i = threadIdx.x; i < 8192; i += 256) {
        int oc = i >> 6, j = i & 63;
        w3T[j * 128 + oc] = w3[i];
    }
}

// spread 3-bit value to bit positions 0,3,6
__device__ __forceinline__ int part3(int v) {
    return (v & 1) | ((v & 2) << 2) | ((v & 4) << 4);
}

#define P4_LIST(X) X(0) X(1) X(2) X(3)

// ---------------------------------------------------------------------------
// Consumer loop: 16-center tasks from a global queue. R12: task->(batch,base)
// mapping is PUBLISH-ORDERED (bb = t&7, base = (t>>3)*16): all 8 producers
// advance s in near-lockstep, so tasks become ready in ~queue order and no
// consumer parks on a far-future task while ready work sits unclaimed (the
// R11 batch-major mapping left ~half the work for a serial tail). Poll with
// s_sleep(64) (4x less atomic-RMW pressure on prog[]). Block = 1024 threads
// = 8 sub-blocks of 128 (2 waves / 2 centers each) — verified bqmlp body.
// ---------------------------------------------------------------------------
__device__ __forceinline__ void consume_tasks(
    char* smemRaw, int* taskS, const float* __restrict__ xyz_all,
    const float4* __restrict__ wsCtr, const float* __restrict__ w1T,
    const float* __restrict__ b1, const float* __restrict__ w2T,
    const float* __restrict__ b2, const float* __restrict__ w3T,
    const float* __restrict__ b3, float* __restrict__ out1,
    int* __restrict__ prog, int* __restrict__ taskCtr) {
    const int tid = threadIdx.x;
    const int l = tid & 63;
    const int sub = tid >> 7;                                   // 0..7
    const int cb = __builtin_amdgcn_readfirstlane((tid >> 6) & 1);
    float* hT = ((float*)smemRaw) + sub * 4096;                 // [64 ch][64 rows]
    float* relF = ((float*)smemRaw) + 8 * 4096 + sub * 192;     // [64 rows][3]

    for (;;) {
        if (tid == 0) *taskS = atomicAdd(taskCtr, 1);
        __syncthreads();
        const int t = *taskS;
        if (t >= NTASKS) break;
        const int bb = t & 7;                 // publish-ordered mapping
        const int base = (t >> 3) << 4;
        if (tid == 0) {
            while (atomicAdd(&prog[bb], 0) < base + 16) __builtin_amdgcn_s_sleep(64);
        }
        __syncthreads();
        __threadfence();  // acquire: invalidate stale lines before reading ctr
        const int s0 = base + sub * 2;
        const float* xyz = xyz_all + (size_t)bb * NN * 3;

        // ---- ball query: wave cb of this sub handles center s0+cb
        {
            float4 cc = wsCtr[(size_t)bb * SS + s0 + cb];
            float ccx = cc.x, ccy = cc.y, ccz = cc.z;
            const float R2 = (float)(0.2 * 0.2);
            int total = 0;
            float fx = 0.f, fy = 0.f, fz = 0.f;
            bool have = false;
            for (int chunk = 0; chunk < 128 && total < KNB; ++chunk) {
                int p = chunk * 64 + l;
                float x = xyz[p * 3 + 0], y = xyz[p * 3 + 1], z = xyz[p * 3 + 2];
                float d = sqdist_exact(ccx, ccy, ccz, x, y, z);
                bool hit = (d <= R2);
                unsigned long long mask = __ballot(hit);
                int cnt = __popcll(mask);
                if (cnt) {
                    int pos = total + __popcll(mask & ((1ull << l) - 1ull));
                    float rx = x - ccx, ry = y - ccy, rz = z - ccz;
                    if (hit && pos < KNB) {
                        relF[(cb * KNB + pos) * 3 + 0] = rx;
                        relF[(cb * KNB + pos) * 3 + 1] = ry;
                        relF[(cb * KNB + pos) * 3 + 2] = rz;
                    }
                    if (hit && pos == 0) { fx = rx; fy = ry; fz = rz; have = true; }
                    total += cnt;
                }
            }
            unsigned long long hm = __ballot(have);
            if (total < KNB) {
                int src = __ffsll((long long)hm) - 1;
                float gx = __shfl(fx, src), gy = __shfl(fy, src), gz = __shfl(fz, src);
                if (l >= total && l < KNB) {
                    relF[(cb * KNB + l) * 3 + 0] = gx;
                    relF[(cb * KNB + l) * 3 + 1] = gy;
                    relF[(cb * KNB + l) * 3 + 2] = gz;
                }
            }
        }
        __syncthreads();

        const int r = l;  // rows 0..31 center s0, rows 32..63 center s0+1

        // ---- layer 1: rel(3) -> 64
        {
            float rx = relF[r * 3 + 0], ry = relF[r * 3 + 1], rz = relF[r * 3 + 2];
#pragma unroll
            for (int i = 0; i < 32; ++i) {
                int ch = cb * 32 + i;
                float h = b1[ch];
                h = fmaf(rx, w1T[0 * 64 + ch], h);
                h = fmaf(ry, w1T[1 * 64 + ch], h);
                h = fmaf(rz, w1T[2 * 64 + ch], h);
                hT[ch * 64 + r] = fmaxf(h, 0.0f);
            }
        }
        __syncthreads();

        // ---- layer 2: 64 -> 64 (h2 overwrites h1 in place after barrier)
        {
            float acc[32];
#pragma unroll
            for (int i = 0; i < 32; ++i) acc[i] = b2[cb * 32 + i];
#pragma unroll 2
            for (int j = 0; j < 64; ++j) {
                float a = hT[j * 64 + r];
                const float4* wrow = (const float4*)(w2T + j * 64 + cb * 32);
#pragma unroll
                for (int i4 = 0; i4 < 8; ++i4) {
                    float4 w = wrow[i4];
                    acc[i4 * 4 + 0] = fmaf(a, w.x, acc[i4 * 4 + 0]);
                    acc[i4 * 4 + 1] = fmaf(a, w.y, acc[i4 * 4 + 1]);
                    acc[i4 * 4 + 2] = fmaf(a, w.z, acc[i4 * 4 + 2]);
                    acc[i4 * 4 + 3] = fmaf(a, w.w, acc[i4 * 4 + 3]);
                }
            }
            __syncthreads();
#pragma unroll
            for (int i = 0; i < 32; ++i) hT[(cb * 32 + i) * 64 + r] = fmaxf(acc[i], 0.0f);
        }
        __syncthreads();

        // ---- layer 3: 64 -> 128 in two 32-channel halves + maxpool + store
#pragma unroll 1
        for (int half = 0; half < 2; ++half) {
            float acc[32];
#pragma unroll
            for (int i = 0; i < 32; ++i) acc[i] = b3[cb * 64 + half * 32 + i];
#pragma unroll 2
            for (int j = 0; j < 64; ++j) {
                float a = hT[j * 64 + r];
                const float4* wrow = (const float4*)(w3T + j * 128 + cb * 64 + half * 32);
#pragma unroll
                for (int i4 = 0; i4 < 8; ++i4) {
                    float4 w = wrow[i4];
                    acc[i4 * 4 + 0] = fmaf(a, w.x, acc[i4 * 4 + 0]);
                    acc[i4 * 4 + 1] = fmaf(a, w.y, acc[i4 * 4 + 1]);
                    acc[i4 * 4 + 2] = fmaf(a, w.z, acc[i4 * 4 + 2]);
                    acc[i4 * 4 + 3] = fmaf(a, w.w, acc[i4 * 4 + 3]);
                }
            }
#pragma unroll
            for (int i = 0; i < 32; ++i) {
                float v = fmaxf(acc[i], 0.0f);
                v = fmaxf(v, __shfl_xor(v, 1));
                v = fmaxf(v, __shfl_xor(v, 2));
                v = fmaxf(v, __shfl_xor(v, 4));
                v = fmaxf(v, __shfl_xor(v, 8));
                v = fmaxf(v, __shfl_xor(v, 16));
                acc[i] = v;
            }
            if ((l & 31) == 0) {
                int sA = s0 + (l >> 5);
                float* op = out1 + ((size_t)bb * 128 + cb * 64 + half * 32) * SS + sA;
#pragma unroll
                for (int i = 0; i < 32; ++i) op[(size_t)i * SS] = acc[i];
            }
        }
        __syncthreads();  // protect relF/hT before next task
    }
}

// ---------------------------------------------------------------------------
// Fused producer-consumer kernel. 256 blocks x 1024 threads, ~134KB LDS ->
// 1 block/CU. Blocks 0..7: R19 FPS (verified, 1552us) + per-iter global
// center store + chunked publish (threadfence + atomicExch every 16 iters).
// Blocks 8..255: consume bqmlp tasks as centers become available. Producers
// fall into the consumer loop when done -> correctness independent of
// scheduling (worst case degenerates to serial = current behavior).
// ---------------------------------------------------------------------------
__global__ __attribute__((amdgpu_flat_work_group_size(1024, 1024)))
void fused_kernel(const float* __restrict__ xyz_all,
                  float4* __restrict__ wsSorted,
                  float4* __restrict__ wsCtr,
                  float* __restrict__ out0,
                  const float* __restrict__ w1T, const float* __restrict__ b1,
                  const float* __restrict__ w2T, const float* __restrict__ b2,
                  const float* __restrict__ w3T, const float* __restrict__ b3,
                  float* __restrict__ out1, int* __restrict__ syncWs) {
    __shared__ __align__(16) char smemRaw[137216];
    __shared__ int taskS;
    int* prog = syncWs;        // [8] published-center counts
    int* taskCtr = syncWs + 8;

    const int tid = threadIdx.x;
    const int wid = tid >> 6;
    const int lane = tid & 63;

    if (blockIdx.x < BB) {
        // ================= producer: FPS for batch b =================
        const int b = blockIdx.x;
        const float* xyz = xyz_all + (size_t)b * NN * 3;
        float4* sorted = wsSorted + (size_t)b * NN;
        float4* ctr = wsCtr + (size_t)b * SS;
        float* o0 = out0 + (size_t)b * 3 * SS;

        float* xLds = (float*)smemRaw;                 // NN
        float* yLds = xLds + NN;
        float* zLds = yLds + NN;
        float4* ctrLds = (float4*)(zLds + NN);         // SS
        int* cellCnt = (int*)(ctrLds + SS);            // 512
        int* cellBase = cellCnt + 512;                 // 512
        unsigned long long* redp = (unsigned long long*)(cellBase + 512);  // [2*16]

        // --- pass 1: Morton-cell counts (8 pts/thread) + stage xyz in LDS
        if (tid < 512) cellCnt[tid] = 0;
        __syncthreads();
        int cellReg[8];
#pragma unroll
        for (int j = 0; j < 8; ++j) {
            int p = tid + j * 1024;
            float x = xyz[p * 3 + 0], y = xyz[p * 3 + 1], z = xyz[p * 3 + 2];
            xLds[p] = x; yLds[p] = y; zLds[p] = z;
            int qx = min(7, (int)(x * 8.0f));
            int qy = min(7, (int)(y * 8.0f));
            int qz = min(7, (int)(z * 8.0f));
            cellReg[j] = part3(qx) | (part3(qy) << 1) | (part3(qz) << 2);
            atomicAdd(&cellCnt[cellReg[j]], 1);
        }
        __syncthreads();
        int myCnt = (tid < 512) ? cellCnt[tid] : 0;
        for (int off = 1; off < 512; off <<= 1) {
            int v = (tid < 512 && tid >= off) ? cellCnt[tid - off] : 0;
            __syncthreads();
            if (tid < 512) cellCnt[tid] += v;
            __syncthreads();
        }
        if (tid < 512) cellBase[tid] = cellCnt[tid] - myCnt;
        __syncthreads();
        // --- pass 2: scatter to global ws in Morton order
#pragma unroll
        for (int j = 0; j < 8; ++j) {
            int p = tid + j * 1024;
            float x = xLds[p], y = yLds[p], z = zLds[p];
            int pos = atomicAdd(&cellBase[cellReg[j]], 1);
            sorted[pos] = make_float4(x, y, z, __int_as_float(p));
        }
        __threadfence();
        __syncthreads();

        // --- 8 bricks as 4 packed pairs
#define DECL_PR(j)                                                   \
        f32x2 px##j, py##j, pz##j, dist##j;                          \
        int ndA##j, ndB##j;                                          \
        {                                                            \
            float4 va = sorted[(wid * 8 + 2 * j) * 64 + lane];       \
            float4 vb = sorted[(wid * 8 + 2 * j + 1) * 64 + lane];   \
            px##j = (f32x2){va.x, vb.x};                             \
            py##j = (f32x2){va.y, vb.y};                             \
            pz##j = (f32x2){va.z, vb.z};                             \
            ndA##j = ~__float_as_int(va.w);                          \
            ndB##j = ~__float_as_int(vb.w);                          \
            dist##j = (f32x2){1e10f, 1e10f};                         \
        }
        P4_LIST(DECL_PR)

        float bbxlo = 0.f, bbxhi = 0.f, bbylo = 0.f, bbyhi = 0.f,
              bbzlo = 0.f, bbzhi = 0.f;
#define BRICK_BB2(j)                                              \
        {                                                         \
            float xl, xh, yl, yh, zl, zh;                         \
            wave_minmax(px##j.x, xl, xh);                         \
            wave_minmax(py##j.x, yl, yh);                         \
            wave_minmax(pz##j.x, zl, zh);                         \
            if (lane == 2 * j) {                                  \
                bbxlo = xl; bbxhi = xh;                           \
                bbylo = yl; bbyhi = yh;                           \
                bbzlo = zl; bbzhi = zh;                           \
            }                                                     \
            wave_minmax(px##j.y, xl, xh);                         \
            wave_minmax(py##j.y, yl, yh);                         \
            wave_minmax(pz##j.y, zl, zh);                         \
            if (lane == 2 * j + 1) {                              \
                bbxlo = xl; bbxhi = xh;                           \
                bbylo = yl; bbyhi = yh;                           \
                bbzlo = zl; bbzhi = zh;                           \
            }                                                     \
        }
        P4_LIST(BRICK_BB2)

        float cx = xLds[0], cy = yLds[0], cz = zLds[0];
        if (tid == 0) {
            float4 c4 = make_float4(cx, cy, cz, 0.0f);
            ctrLds[0] = c4;
            ctr[0] = c4;
        }

        unsigned long long waveKey =
            ((unsigned long long)__float_as_uint(1e10f) << 32) | 0xFFFFFFFFull;
        float wave_bv = 1e10f;

        for (int s = 1; s < SS; ++s) {
            const int par = s & 1;
            float ddx = fmaxf(fmaxf(bbxlo - cx, cx - bbxhi), 0.0f);
            float ddy = fmaxf(fmaxf(bbylo - cy, cy - bbyhi), 0.0f);
            float ddz = fmaxf(fmaxf(bbzlo - cz, cz - bbzhi), 0.0f);
            float lb2 = (ddx * ddx + ddy * ddy) + ddz * ddz;
            bool act = (lane < 8) && (lb2 * 0.999f < wave_bv);
            if (__ballot(act)) {
                const f32x2 c2x = (f32x2){cx, cx};
                const f32x2 c2y = (f32x2){cy, cy};
                const f32x2 c2z = (f32x2){cz, cz};
#define UPD_PR(j)                                                        \
                {                                                        \
                    f32x2 d = sqdist2_exact(px##j, py##j, pz##j, c2x, c2y, c2z); \
                    dist##j.x = fminf(dist##j.x, d.x);                   \
                    dist##j.y = fminf(dist##j.y, d.y);                   \
                }
                P4_LIST(UPD_PR)
#define KEY_PR(j)                                                        \
                unsigned long long kA##j =                               \
                    ((unsigned long long)__float_as_uint(dist##j.x) << 32) | \
                    (unsigned)ndA##j;                                    \
                unsigned long long kB##j =                               \
                    ((unsigned long long)__float_as_uint(dist##j.y) << 32) | \
                    (unsigned)ndB##j;
                P4_LIST(KEY_PR)
                unsigned long long t0 = u64max(kA0, kB0), t1 = u64max(kA1, kB1),
                                   t2 = u64max(kA2, kB2), t3 = u64max(kA3, kB3);
                unsigned long long K = u64max(u64max(t0, t1), u64max(t2, t3));
                K = dpp_u64max_step<ROW_SHR1>(K);
                K = dpp_u64max_step<ROW_SHR2>(K);
                K = dpp_u64max_step<ROW_SHR4>(K);
                K = dpp_u64max_step<ROW_SHR8>(K);
                K = dpp_u64max_step<ROW_BC15>(K);
                K = dpp_u64max_step<ROW_BC31>(K);
                if (lane == 63) redp[par * 16 + wid] = K;
                unsigned wlo = (unsigned)__builtin_amdgcn_readlane(
                    (int)(unsigned)(K & 0xffffffffu), 63);
                unsigned whi = (unsigned)__builtin_amdgcn_readlane(
                    (int)(unsigned)(K >> 32), 63);
                waveKey = ((unsigned long long)whi << 32) | wlo;
                wave_bv = __int_as_float((int)whi);
            } else {
                if (lane == 0) redp[par * 16 + wid] = waveKey;
            }
            __syncthreads();
            unsigned long long k = redp[par * 16 + (lane & 15)];
            k = dpp_u64max_step<ROW_SHR1>(k);
            k = dpp_u64max_step<ROW_SHR2>(k);
            k = dpp_u64max_step<ROW_SHR4>(k);
            k = dpp_u64max_step<ROW_SHR8>(k);
            unsigned blo = (unsigned)__builtin_amdgcn_readlane(
                (int)(unsigned)(k & 0xffffffffu), 15);
            int wiu = (int)(~blo);
            cx = xLds[wiu];
            cy = yLds[wiu];
            cz = zLds[wiu];
            if (tid == 0) {
                float4 c4 = make_float4(cx, cy, cz, 0.0f);
                ctrLds[s] = c4;
                ctr[s] = c4;  // publish progressively for consumers
            }
            if ((s & 15) == 15 && wid == 0) {
                __threadfence();  // release: centers [0, s] globally visible
                if (lane == 0) atomicExch(&prog[b], s + 1);
            }
        }

        // --- write new_xyz output (centers already in wsCtr)
        __syncthreads();
        for (int s = tid; s < SS; s += 1024) {
            float4 c = ctrLds[s];
            o0[s] = c.x;
            o0[SS + s] = c.y;
            o0[2 * SS + s] = c.z;
        }
        // help drain remaining consumer tasks (also guarantees completion
        // regardless of block scheduling)
        consume_tasks(smemRaw, &taskS, xyz_all, wsCtr, w1T, b1, w2T, b2,
                      w3T, b3, out1, prog, taskCtr);
    } else {
        // ================= consumer =================
        consume_tasks(smemRaw, &taskS, xyz_all, wsCtr, w1T, b1, w2T, b2,
                      w3T, b3, out1, prog, taskCtr);
    }
}

extern "C" void kernel_launch(void* const* d_in, const int* in_sizes, int n_in,
                              void* d_out, int out_size, void* d_ws, size_t ws_size,
                              hipStream_t stream) {
    (void)in_sizes; (void)n_in; (void)out_size; (void)ws_size;
    const float* xyz = (const float*)d_in[0];
    // d_in[1] = features : unused by the reference
    const float* w1 = (const float*)d_in[2];
    const float* b1 = (const float*)d_in[3];
    const float* w2 = (const float*)d_in[4];
    const float* b2 = (const float*)d_in[5];
    const float* w3 = (const float*)d_in[6];
    const float* b3 = (const float*)d_in[7];
    float* out = (float*)d_out;

    // workspace layout
    float4* wsCtr = (float4*)d_ws;              // B*S float4      (256 KB)
    float4* wsSorted = wsCtr + BB * SS;         // B*N float4      (1 MB)
    float* w1T = (float*)(wsSorted + BB * NN);  // 192 f
    float* w2T = w1T + 192;                     // 4096 f
    float* w3T = w2T + 4096;                    // 8192 f
    int* syncWs = (int*)(w3T + 8192);           // 12 ints (prog[8] + taskCtr)

    prep_kernel<<<1, 256, 0, stream>>>(w1, w2, w3, w1T, w2T, w3T, syncWs);
    fused_kernel<<<256, 1024, 0, stream>>>(xyz, wsSorted, wsCtr, out,
                                           w1T, b1, w2T, b2, w3T, b3,
                                           out + BB * 3 * SS, syncWs);
}

// Round 14
// 1697.986 us; speedup vs baseline: 1.5072x; 1.0187x over previous
//
#include <hip/hip_runtime.h>
#include <cstdint>
#include <cstddef>

#define BB 8
#define NN 8192
#define SS 2048
#define KNB 32
#define NTASKS (BB * (SS / 16))

typedef float f32x2 __attribute__((ext_vector_type(2)));

// Bit-exact squared distance matching numpy: (a-b) per component, squares,
// left-to-right sum, no FMA contraction.
__device__ __forceinline__ float sqdist_exact(float ax, float ay, float az,
                                              float bx, float by, float bz) {
#pragma clang fp contract(off)
    float dx = ax - bx;
    float dy = ay - by;
    float dz = az - bz;
    return (dx * dx + dy * dy) + dz * dz;
}

// Packed 2-wide exact sqdist: same op order per component, no contraction.
__device__ __forceinline__ f32x2 sqdist2_exact(f32x2 px, f32x2 py, f32x2 pz,
                                               f32x2 cx2, f32x2 cy2, f32x2 cz2) {
#pragma clang fp contract(off)
    f32x2 dx = px - cx2;
    f32x2 dy = py - cy2;
    f32x2 dz = pz - cz2;
    return (dx * dx + dy * dy) + dz * dz;
}

// u64 max (compare-select, branchless)
__device__ __forceinline__ unsigned long long u64max(unsigned long long a,
                                                     unsigned long long b) {
    return (a > b) ? a : b;
}

// DPP u64 max step (row_shr/row_bcast legal on CDNA4). Identity 0 safe.
template <int CTRL>
__device__ __forceinline__ unsigned long long dpp_u64max_step(unsigned long long k) {
    int lo = __builtin_amdgcn_update_dpp(0, (int)(unsigned)(k & 0xffffffffu),
                                         CTRL, 0xf, 0xf, false);
    int hi = __builtin_amdgcn_update_dpp(0, (int)(unsigned)(k >> 32),
                                         CTRL, 0xf, 0xf, false);
    unsigned long long o = ((unsigned long long)(unsigned)hi << 32) | (unsigned)lo;
    return (o > k) ? o : k;
}
#define ROW_SHR1 0x111
#define ROW_SHR2 0x112
#define ROW_SHR4 0x114
#define ROW_SHR8 0x118
#define ROW_BC15 0x142
#define ROW_BC31 0x143

// full-wave min/max butterfly (init-time only)
__device__ __forceinline__ void wave_minmax(float x, float& lo, float& hi) {
    float a = x, b = x;
#pragma unroll
    for (int off = 1; off < 64; off <<= 1) {
        a = fminf(a, __shfl_xor(a, off));
        b = fmaxf(b, __shfl_xor(b, off));
    }
    lo = a;
    hi = b;
}

// ---------------------------------------------------------------------------
// Weight transpose prep + zero the producer/consumer sync area (runs at the
// head of every launch/replay, so re-runs are self-initializing).
// syncWs layout: prog[b] at syncWs[b*32] (128B apart, one line per batch);
// taskCtr at syncWs[256].
// ---------------------------------------------------------------------------
__global__ void prep_kernel(const float* __restrict__ w1, const float* __restrict__ w2,
                            const float* __restrict__ w3, float* __restrict__ w1T,
                            float* __restrict__ w2T, float* __restrict__ w3T,
                            int* __restrict__ syncWs) {
    for (int i = threadIdx.x; i < 288; i += 256) syncWs[i] = 0;
    for (int i = threadIdx.x; i < 192; i += 256) {
        int oc = i / 3, c = i % 3;
        w1T[c * 64 + oc] = w1[i];
    }
    for (int i = threadIdx.x; i < 4096; i += 256) {
        int oc = i >> 6, j = i & 63;
        w2T[j * 64 + oc] = w2[i];
    }
    for (int i = threadIdx.x; i < 8192; i += 256) {
        int oc = i >> 6, j = i & 63;
        w3T[j * 128 + oc] = w3[i];
    }
}

// spread 3-bit value to bit positions 0,3,6
__device__ __forceinline__ int part3(int v) {
    return (v & 1) | ((v & 2) << 2) | ((v & 4) << 4);
}

#define P4_LIST(X) X(0) X(1) X(2) X(3)

// ---------------------------------------------------------------------------
// Consumer loop. R14: poll with a RELAXED AGENT-scope atomic LOAD (coherent-
// point read, no exclusive line ownership — the R13 atomicAdd(,0) RMWs from
// 248 blocks serialized on prog's line and the producer's exch queued behind
// them). prog is padded 128B/batch. Monotonic-flag polling is safe with any
// eventually-visible load; the acquire threadfence before data reads is
// unchanged (pattern verified absmax=0 in R11/R13).
// ---------------------------------------------------------------------------
__device__ __forceinline__ void consume_tasks(
    char* smemRaw, int* taskS, const float* __restrict__ xyz_all,
    const float4* __restrict__ wsCtr, const float* __restrict__ w1T,
    const float* __restrict__ b1, const float* __restrict__ w2T,
    const float* __restrict__ b2, const float* __restrict__ w3T,
    const float* __restrict__ b3, float* __restrict__ out1,
    int* __restrict__ prog, int* __restrict__ taskCtr) {
    const int tid = threadIdx.x;
    const int l = tid & 63;
    const int sub = tid >> 7;                                   // 0..7
    const int cb = __builtin_amdgcn_readfirstlane((tid >> 6) & 1);
    float* hT = ((float*)smemRaw) + sub * 4096;                 // [64 ch][64 rows]
    float* relF = ((float*)smemRaw) + 8 * 4096 + sub * 192;     // [64 rows][3]

    for (;;) {
        if (tid == 0) *taskS = atomicAdd(taskCtr, 1);
        __syncthreads();
        const int t = *taskS;
        if (t >= NTASKS) break;
        const int bb = t & 7;                 // publish-ordered mapping
        const int base = (t >> 3) << 4;
        if (tid == 0) {
            while (__hip_atomic_load(&prog[bb * 32], __ATOMIC_RELAXED,
                                     __HIP_MEMORY_SCOPE_AGENT) < base + 16)
                __builtin_amdgcn_s_sleep(64);
        }
        __syncthreads();
        __threadfence();  // acquire: invalidate stale lines before reading ctr
        const int s0 = base + sub * 2;
        const float* xyz = xyz_all + (size_t)bb * NN * 3;

        // ---- ball query: wave cb of this sub handles center s0+cb
        {
            float4 cc = wsCtr[(size_t)bb * SS + s0 + cb];
            float ccx = cc.x, ccy = cc.y, ccz = cc.z;
            const float R2 = (float)(0.2 * 0.2);
            int total = 0;
            float fx = 0.f, fy = 0.f, fz = 0.f;
            bool have = false;
            for (int chunk = 0; chunk < 128 && total < KNB; ++chunk) {
                int p = chunk * 64 + l;
                float x = xyz[p * 3 + 0], y = xyz[p * 3 + 1], z = xyz[p * 3 + 2];
                float d = sqdist_exact(ccx, ccy, ccz, x, y, z);
                bool hit = (d <= R2);
                unsigned long long mask = __ballot(hit);
                int cnt = __popcll(mask);
                if (cnt) {
                    int pos = total + __popcll(mask & ((1ull << l) - 1ull));
                    float rx = x - ccx, ry = y - ccy, rz = z - ccz;
                    if (hit && pos < KNB) {
                        relF[(cb * KNB + pos) * 3 + 0] = rx;
                        relF[(cb * KNB + pos) * 3 + 1] = ry;
                        relF[(cb * KNB + pos) * 3 + 2] = rz;
                    }
                    if (hit && pos == 0) { fx = rx; fy = ry; fz = rz; have = true; }
                    total += cnt;
                }
            }
            unsigned long long hm = __ballot(have);
            if (total < KNB) {
                int src = __ffsll((long long)hm) - 1;
                float gx = __shfl(fx, src), gy = __shfl(fy, src), gz = __shfl(fz, src);
                if (l >= total && l < KNB) {
                    relF[(cb * KNB + l) * 3 + 0] = gx;
                    relF[(cb * KNB + l) * 3 + 1] = gy;
                    relF[(cb * KNB + l) * 3 + 2] = gz;
                }
            }
        }
        __syncthreads();

        const int r = l;  // rows 0..31 center s0, rows 32..63 center s0+1

        // ---- layer 1: rel(3) -> 64
        {
            float rx = relF[r * 3 + 0], ry = relF[r * 3 + 1], rz = relF[r * 3 + 2];
#pragma unroll
            for (int i = 0; i < 32; ++i) {
                int ch = cb * 32 + i;
                float h = b1[ch];
                h = fmaf(rx, w1T[0 * 64 + ch], h);
                h = fmaf(ry, w1T[1 * 64 + ch], h);
                h = fmaf(rz, w1T[2 * 64 + ch], h);
                hT[ch * 64 + r] = fmaxf(h, 0.0f);
            }
        }
        __syncthreads();

        // ---- layer 2: 64 -> 64 (h2 overwrites h1 in place after barrier)
        {
            float acc[32];
#pragma unroll
            for (int i = 0; i < 32; ++i) acc[i] = b2[cb * 32 + i];
#pragma unroll 2
            for (int j = 0; j < 64; ++j) {
                float a = hT[j * 64 + r];
                const float4* wrow = (const float4*)(w2T + j * 64 + cb * 32);
#pragma unroll
                for (int i4 = 0; i4 < 8; ++i4) {
                    float4 w = wrow[i4];
                    acc[i4 * 4 + 0] = fmaf(a, w.x, acc[i4 * 4 + 0]);
                    acc[i4 * 4 + 1] = fmaf(a, w.y, acc[i4 * 4 + 1]);
                    acc[i4 * 4 + 2] = fmaf(a, w.z, acc[i4 * 4 + 2]);
                    acc[i4 * 4 + 3] = fmaf(a, w.w, acc[i4 * 4 + 3]);
                }
            }
            __syncthreads();
#pragma unroll
            for (int i = 0; i < 32; ++i) hT[(cb * 32 + i) * 64 + r] = fmaxf(acc[i], 0.0f);
        }
        __syncthreads();

        // ---- layer 3: 64 -> 128 in two 32-channel halves + maxpool + store
#pragma unroll 1
        for (int half = 0; half < 2; ++half) {
            float acc[32];
#pragma unroll
            for (int i = 0; i < 32; ++i) acc[i] = b3[cb * 64 + half * 32 + i];
#pragma unroll 2
            for (int j = 0; j < 64; ++j) {
                float a = hT[j * 64 + r];
                const float4* wrow = (const float4*)(w3T + j * 128 + cb * 64 + half * 32);
#pragma unroll
                for (int i4 = 0; i4 < 8; ++i4) {
                    float4 w = wrow[i4];
                    acc[i4 * 4 + 0] = fmaf(a, w.x, acc[i4 * 4 + 0]);
                    acc[i4 * 4 + 1] = fmaf(a, w.y, acc[i4 * 4 + 1]);
                    acc[i4 * 4 + 2] = fmaf(a, w.z, acc[i4 * 4 + 2]);
                    acc[i4 * 4 + 3] = fmaf(a, w.w, acc[i4 * 4 + 3]);
                }
            }
#pragma unroll
            for (int i = 0; i < 32; ++i) {
                float v = fmaxf(acc[i], 0.0f);
                v = fmaxf(v, __shfl_xor(v, 1));
                v = fmaxf(v, __shfl_xor(v, 2));
                v = fmaxf(v, __shfl_xor(v, 4));
                v = fmaxf(v, __shfl_xor(v, 8));
                v = fmaxf(v, __shfl_xor(v, 16));
                acc[i] = v;
            }
            if ((l & 31) == 0) {
                int sA = s0 + (l >> 5);
                float* op = out1 + ((size_t)bb * 128 + cb * 64 + half * 32) * SS + sA;
#pragma unroll
                for (int i = 0; i < 32; ++i) op[(size_t)i * SS] = acc[i];
            }
        }
        __syncthreads();  // protect relF/hT before next task
    }
}

// ---------------------------------------------------------------------------
// Fused producer-consumer kernel. R14 producer-side change: EPOCH-LAGGED
// publish. No per-iteration ctr store. At s%16==15, wave 0 does:
//   fence (waits only epoch-old stores -> ~0cy) -> atomicExch(prog, s-15)
//   -> issue coalesced ctr stores for the CURRENT chunk [s-15, s] (lanes
//   0..15 from ctrLds). Chunk-k stores are thus fenced before the exch that
//   publishes chunk k (at epoch k+1) — same ordering guarantee as R13's
//   verified pattern, but the vmcnt wait is off the critical path. Final
//   fence+exch(SS) after the loop covers the last chunk.
// ---------------------------------------------------------------------------
__global__ __attribute__((amdgpu_flat_work_group_size(1024, 1024)))
void fused_kernel(const float* __restrict__ xyz_all,
                  float4* __restrict__ wsSorted,
                  float4* __restrict__ wsCtr,
                  float* __restrict__ out0,
                  const float* __restrict__ w1T, const float* __restrict__ b1,
                  const float* __restrict__ w2T, const float* __restrict__ b2,
                  const float* __restrict__ w3T, const float* __restrict__ b3,
                  float* __restrict__ out1, int* __restrict__ syncWs) {
    __shared__ __align__(16) char smemRaw[137216];
    __shared__ int taskS;
    int* prog = syncWs;           // prog[b] at syncWs[b*32]
    int* taskCtr = syncWs + 256;

    const int tid = threadIdx.x;
    const int wid = tid >> 6;
    const int lane = tid & 63;

    if (blockIdx.x < BB) {
        // ================= producer: FPS for batch b =================
        const int b = blockIdx.x;
        const float* xyz = xyz_all + (size_t)b * NN * 3;
        float4* sorted = wsSorted + (size_t)b * NN;
        float4* ctr = wsCtr + (size_t)b * SS;
        float* o0 = out0 + (size_t)b * 3 * SS;

        float* xLds = (float*)smemRaw;                 // NN
        float* yLds = xLds + NN;
        float* zLds = yLds + NN;
        float4* ctrLds = (float4*)(zLds + NN);         // SS
        int* cellCnt = (int*)(ctrLds + SS);            // 512
        int* cellBase = cellCnt + 512;                 // 512
        unsigned long long* redp = (unsigned long long*)(cellBase + 512);  // [2*16]

        // --- pass 1: Morton-cell counts (8 pts/thread) + stage xyz in LDS
        if (tid < 512) cellCnt[tid] = 0;
        __syncthreads();
        int cellReg[8];
#pragma unroll
        for (int j = 0; j < 8; ++j) {
            int p = tid + j * 1024;
            float x = xyz[p * 3 + 0], y = xyz[p * 3 + 1], z = xyz[p * 3 + 2];
            xLds[p] = x; yLds[p] = y; zLds[p] = z;
            int qx = min(7, (int)(x * 8.0f));
            int qy = min(7, (int)(y * 8.0f));
            int qz = min(7, (int)(z * 8.0f));
            cellReg[j] = part3(qx) | (part3(qy) << 1) | (part3(qz) << 2);
            atomicAdd(&cellCnt[cellReg[j]], 1);
        }
        __syncthreads();
        int myCnt = (tid < 512) ? cellCnt[tid] : 0;
        for (int off = 1; off < 512; off <<= 1) {
            int v = (tid < 512 && tid >= off) ? cellCnt[tid - off] : 0;
            __syncthreads();
            if (tid < 512) cellCnt[tid] += v;
            __syncthreads();
        }
        if (tid < 512) cellBase[tid] = cellCnt[tid] - myCnt;
        __syncthreads();
        // --- pass 2: scatter to global ws in Morton order
#pragma unroll
        for (int j = 0; j < 8; ++j) {
            int p = tid + j * 1024;
            float x = xLds[p], y = yLds[p], z = zLds[p];
            int pos = atomicAdd(&cellBase[cellReg[j]], 1);
            sorted[pos] = make_float4(x, y, z, __int_as_float(p));
        }
        __threadfence();
        __syncthreads();

        // --- 8 bricks as 4 packed pairs
#define DECL_PR(j)                                                   \
        f32x2 px##j, py##j, pz##j, dist##j;                          \
        int ndA##j, ndB##j;                                          \
        {                                                            \
            float4 va = sorted[(wid * 8 + 2 * j) * 64 + lane];       \
            float4 vb = sorted[(wid * 8 + 2 * j + 1) * 64 + lane];   \
            px##j = (f32x2){va.x, vb.x};                             \
            py##j = (f32x2){va.y, vb.y};                             \
            pz##j = (f32x2){va.z, vb.z};                             \
            ndA##j = ~__float_as_int(va.w);                          \
            ndB##j = ~__float_as_int(vb.w);                          \
            dist##j = (f32x2){1e10f, 1e10f};                         \
        }
        P4_LIST(DECL_PR)

        float bbxlo = 0.f, bbxhi = 0.f, bbylo = 0.f, bbyhi = 0.f,
              bbzlo = 0.f, bbzhi = 0.f;
#define BRICK_BB2(j)                                              \
        {                                                         \
            float xl, xh, yl, yh, zl, zh;                         \
            wave_minmax(px##j.x, xl, xh);                         \
            wave_minmax(py##j.x, yl, yh);                         \
            wave_minmax(pz##j.x, zl, zh);                         \
            if (lane == 2 * j) {                                  \
                bbxlo = xl; bbxhi = xh;                           \
                bbylo = yl; bbyhi = yh;                           \
                bbzlo = zl; bbzhi = zh;                           \
            }                                                     \
            wave_minmax(px##j.y, xl, xh);                         \
            wave_minmax(py##j.y, yl, yh);                         \
            wave_minmax(pz##j.y, zl, zh);                         \
            if (lane == 2 * j + 1) {                              \
                bbxlo = xl; bbxhi = xh;                           \
                bbylo = yl; bbyhi = yh;                           \
                bbzlo = zl; bbzhi = zh;                           \
            }                                                     \
        }
        P4_LIST(BRICK_BB2)

        float cx = xLds[0], cy = yLds[0], cz = zLds[0];
        if (tid == 0) ctrLds[0] = make_float4(cx, cy, cz, 0.0f);

        unsigned long long waveKey =
            ((unsigned long long)__float_as_uint(1e10f) << 32) | 0xFFFFFFFFull;
        float wave_bv = 1e10f;

        for (int s = 1; s < SS; ++s) {
            const int par = s & 1;
            float ddx = fmaxf(fmaxf(bbxlo - cx, cx - bbxhi), 0.0f);
            float ddy = fmaxf(fmaxf(bbylo - cy, cy - bbyhi), 0.0f);
            float ddz = fmaxf(fmaxf(bbzlo - cz, cz - bbzhi), 0.0f);
            float lb2 = (ddx * ddx + ddy * ddy) + ddz * ddz;
            bool act = (lane < 8) && (lb2 * 0.999f < wave_bv);
            if (__ballot(act)) {
                const f32x2 c2x = (f32x2){cx, cx};
                const f32x2 c2y = (f32x2){cy, cy};
                const f32x2 c2z = (f32x2){cz, cz};
#define UPD_PR(j)                                                        \
                {                                                        \
                    f32x2 d = sqdist2_exact(px##j, py##j, pz##j, c2x, c2y, c2z); \
                    dist##j.x = fminf(dist##j.x, d.x);                   \
                    dist##j.y = fminf(dist##j.y, d.y);                   \
                }
                P4_LIST(UPD_PR)
#define KEY_PR(j)                                                        \
                unsigned long long kA##j =                               \
                    ((unsigned long long)__float_as_uint(dist##j.x) << 32) | \
                    (unsigned)ndA##j;                                    \
                unsigned long long kB##j =                               \
                    ((unsigned long long)__float_as_uint(dist##j.y) << 32) | \
                    (unsigned)ndB##j;
                P4_LIST(KEY_PR)
                unsigned long long t0 = u64max(kA0, kB0), t1 = u64max(kA1, kB1),
                                   t2 = u64max(kA2, kB2), t3 = u64max(kA3, kB3);
                unsigned long long K = u64max(u64max(t0, t1), u64max(t2, t3));
                K = dpp_u64max_step<ROW_SHR1>(K);
                K = dpp_u64max_step<ROW_SHR2>(K);
                K = dpp_u64max_step<ROW_SHR4>(K);
                K = dpp_u64max_step<ROW_SHR8>(K);
                K = dpp_u64max_step<ROW_BC15>(K);
                K = dpp_u64max_step<ROW_BC31>(K);
                if (lane == 63) redp[par * 16 + wid] = K;
                unsigned wlo = (unsigned)__builtin_amdgcn_readlane(
                    (int)(unsigned)(K & 0xffffffffu), 63);
                unsigned whi = (unsigned)__builtin_amdgcn_readlane(
                    (int)(unsigned)(K >> 32), 63);
                waveKey = ((unsigned long long)whi << 32) | wlo;
                wave_bv = __int_as_float((int)whi);
            } else {
                if (lane == 0) redp[par * 16 + wid] = waveKey;
            }
            __syncthreads();
            unsigned long long k = redp[par * 16 + (lane & 15)];
            k = dpp_u64max_step<ROW_SHR1>(k);
            k = dpp_u64max_step<ROW_SHR2>(k);
            k = dpp_u64max_step<ROW_SHR4>(k);
            k = dpp_u64max_step<ROW_SHR8>(k);
            unsigned blo = (unsigned)__builtin_amdgcn_readlane(
                (int)(unsigned)(k & 0xffffffffu), 15);
            int wiu = (int)(~blo);
            cx = xLds[wiu];
            cy = yLds[wiu];
            cz = zLds[wiu];
            if (tid == 0) ctrLds[s] = make_float4(cx, cy, cz, 0.0f);
            if ((s & 15) == 15 && wid == 0) {
                // epoch-lagged publish: fence waits only epoch-old stores
                __threadfence();
                if (lane == 0) atomicExch(&prog[b * 32], s - 15);
                int cs = s - 15 + lane;
                if (lane < 16) ctr[cs] = ctrLds[cs];  // issue chunk-k stores
            }
        }

        // final publish: last chunk's stores fenced, then full count
        if (wid == 0) {
            __threadfence();
            if (lane == 0) atomicExch(&prog[b * 32], SS);
        }

        // --- write new_xyz output (centers already in wsCtr)
        __syncthreads();
        for (int s = tid; s < SS; s += 1024) {
            float4 c = ctrLds[s];
            o0[s] = c.x;
            o0[SS + s] = c.y;
            o0[2 * SS + s] = c.z;
        }
        // help drain remaining consumer tasks (also guarantees completion
        // regardless of block scheduling)
        consume_tasks(smemRaw, &taskS, xyz_all, wsCtr, w1T, b1, w2T, b2,
                      w3T, b3, out1, prog, taskCtr);
    } else {
        // ================= consumer =================
        consume_tasks(smemRaw, &taskS, xyz_all, wsCtr, w1T, b1, w2T, b2,
                      w3T, b3, out1, prog, taskCtr);
    }
}

extern "C" void kernel_launch(void* const* d_in, const int* in_sizes, int n_in,
                              void* d_out, int out_size, void* d_ws, size_t ws_size,
                              hipStream_t stream) {
    (void)in_sizes; (void)n_in; (void)out_size; (void)ws_size;
    const float* xyz = (const float*)d_in[0];
    // d_in[1] = features : unused by the reference
    const float* w1 = (const float*)d_in[2];
    const float* b1 = (const float*)d_in[3];
    const float* w2 = (const float*)d_in[4];
    const float* b2 = (const float*)d_in[5];
    const float* w3 = (const float*)d_in[6];
    const float* b3 = (const float*)d_in[7];
    float* out = (float*)d_out;

    // workspace layout
    float4* wsCtr = (float4*)d_ws;              // B*S float4      (256 KB)
    float4* wsSorted = wsCtr + BB * SS;         // B*N float4      (1 MB)
    float* w1T = (float*)(wsSorted + BB * NN);  // 192 f
    float* w2T = w1T + 192;                     // 4096 f
    float* w3T = w2T + 4096;                    // 8192 f
    int* syncWs = (int*)(w3T + 8192);           // 288 ints (padded prog + taskCtr)

    prep_kernel<<<1, 256, 0, stream>>>(w1, w2, w3, w1T, w2T, w3T, syncWs);
    fused_kernel<<<256, 1024, 0, stream>>>(xyz, wsSorted, wsCtr, out,
                                           w1T, b1, w2T, b2, w3T, b3,
                                           out + BB * 3 * SS, syncWs);
}